// Round 7
// baseline (882.471 us; speedup 1.0000x reference)
//
#include <hip/hip_runtime.h>

typedef unsigned short u16;
typedef __attribute__((ext_vector_type(8))) short bf16x8;
typedef __attribute__((ext_vector_type(4))) float f32x4;

__device__ __forceinline__ u16 f2bf(float f) {
  union { float f; unsigned u; } v; v.f = f;
  unsigned u = v.u;
  u += 0x7fffu + ((u >> 16) & 1u);
  return (u16)(u >> 16);
}

__device__ __forceinline__ void gll16(const void* g, void* l) {
  __builtin_amdgcn_global_load_lds(
      (const __attribute__((address_space(1))) void*)g,
      (__attribute__((address_space(3))) void*)l, 16, 0, 0);
}

// ---------------------------------------------------------------------------
// P1: x[b][c][n] f32 -> xt[b][n][c] bf16   (C=512, N=1600), both inputs
// ---------------------------------------------------------------------------
__global__ __launch_bounds__(256) void transp_cast_x2(const float* __restrict__ ex,
                                                      const float* __restrict__ qu,
                                                      u16* __restrict__ xte,
                                                      u16* __restrict__ xtq) {
  __shared__ float t[32][33];
  int z = blockIdx.z;
  int b = z & 15;
  const float* xb = (z < 16 ? ex : qu) + (size_t)b * 819200;
  u16* xtb = (z < 16 ? xte : xtq) + (size_t)b * 819200;
  int n0 = blockIdx.x * 32, c0 = blockIdx.y * 32;
  int tx = threadIdx.x & 31, ty = threadIdx.x >> 5;
#pragma unroll
  for (int k = 0; k < 4; k++) {
    int c = ty + k * 8;
    t[c][tx] = xb[(size_t)(c0 + c) * 1600 + n0 + tx];
  }
  __syncthreads();
#pragma unroll
  for (int k = 0; k < 4; k++) {
    int n = ty + k * 8;
    xtb[(size_t)(n0 + n) * 512 + c0 + tx] = f2bf(t[tx][n]);
  }
}

// P2: cast w_e / w_q (256x512 each) to bf16
__global__ void cast_w(const float* __restrict__ we, const float* __restrict__ wq,
                       u16* __restrict__ oe, u16* __restrict__ oq) {
  int i = blockIdx.x * 256 + threadIdx.x;
  oe[i] = f2bf(we[i]);
  oq[i] = f2bf(wq[i]);
}

// P3: w[o][c][ky][kx] f32 -> wr[o][t*512+c] bf16 (both conv weights)
__global__ void repack_wc(const float* __restrict__ w1, const float* __restrict__ w2,
                          u16* __restrict__ o1, u16* __restrict__ o2) {
  const float* w = blockIdx.y ? w2 : w1;
  u16* wr = blockIdx.y ? o2 : o1;
  int idx = blockIdx.x * 256 + threadIdx.x;  // 2359296 total
  int o = idx / 4608;
  int r = idx - o * 4608;
  int t = r >> 9;
  int c = r & 511;
  wr[idx] = f2bf(w[o * 4608 + c * 9 + t]);
}

// P4: zero att buffers + Z buffers
__global__ void zero_mem(uint4* __restrict__ p, long n) {
  long i = (long)blockIdx.x * blockDim.x + threadIdx.x;
  long stride = (long)gridDim.x * blockDim.x;
  uint4 z; z.x = 0; z.y = 0; z.z = 0; z.w = 0;
  for (; i < n; i += stride) p[i] = z;
}

// ---------------------------------------------------------------------------
// Generic A*B^T bf16 GEMM, 128x128 tile, BK=64, XOR-swizzled LDS,
// dual problem sets selected by blockIdx.z (z<16 -> set1, else set2).
// MODE 0: store bf16 C[i*N+j].
// ---------------------------------------------------------------------------
template <int MODE>
__global__ __launch_bounds__(256) void gemm_bt64(
    const u16* __restrict__ A, const u16* __restrict__ B, u16* __restrict__ C,
    const u16* __restrict__ A2, const u16* __restrict__ B2, u16* __restrict__ C2,
    int M, int N, int K, long sA, long sB, long sC) {
  __shared__ u16 lds_a[128 * 64];
  __shared__ u16 lds_b[128 * 64];
  int tid = threadIdx.x;
  int z = blockIdx.z, b = z & 15;
  const u16* Ab = (z < 16 ? A : A2) + (size_t)b * sA;
  const u16* Bb = (z < 16 ? B : B2) + (size_t)b * sB;
  u16* Cb = (z < 16 ? C : C2) + (size_t)b * sC;
  int m0 = blockIdx.x * 128, n0 = blockIdx.y * 128;

  int rsub = tid >> 3;                     // 0..31
  int gch = (tid & 7) ^ (rsub & 7);        // swizzled 16B chunk to fetch
  long Kb = (long)K * 2;
  const char* pa[4];
  const char* pb[4];
#pragma unroll
  for (int c = 0; c < 4; c++) {
    int ra = m0 + 32 * c + rsub; ra = ra < M ? ra : M - 1;
    int rb = n0 + 32 * c + rsub; rb = rb < N ? rb : N - 1;
    pa[c] = (const char*)Ab + (long)ra * Kb + gch * 16;
    pb[c] = (const char*)Bb + (long)rb * Kb + gch * 16;
  }

  const f32x4 fzero = {0.f, 0.f, 0.f, 0.f};
  f32x4 acc[4][4];
#pragma unroll
  for (int mi = 0; mi < 4; mi++)
#pragma unroll
    for (int ni = 0; ni < 4; ni++) acc[mi][ni] = fzero;

  int wid = tid >> 6, lane = tid & 63;
  int wm = wid & 1, wn = wid >> 1;
  int lrow = lane & 15, lquad = lane >> 4;
  int sl = lrow & 7;

  int ksteps = K >> 6;
  for (int ks = 0; ks < ksteps; ks++) {
#pragma unroll
    for (int c = 0; c < 4; c++) {
      gll16(pa[c], (char*)lds_a + c * 4096 + tid * 16);
      gll16(pb[c], (char*)lds_b + c * 4096 + tid * 16);
      pa[c] += 128; pb[c] += 128;
    }
    __syncthreads();
#pragma unroll
    for (int k2 = 0; k2 < 2; k2++) {
      int sel = ((k2 << 2) | lquad) ^ sl;
      bf16x8 bv[4];
#pragma unroll
      for (int ni = 0; ni < 4; ni++) {
        int rowb = wn * 64 + ni * 16 + lrow;
        bv[ni] = *(const bf16x8*)((const char*)lds_b + rowb * 128 + sel * 16);
      }
#pragma unroll
      for (int mi = 0; mi < 4; mi++) {
        int rowa = wm * 64 + mi * 16 + lrow;
        bf16x8 av = *(const bf16x8*)((const char*)lds_a + rowa * 128 + sel * 16);
#pragma unroll
        for (int ni = 0; ni < 4; ni++)
          acc[mi][ni] =
              __builtin_amdgcn_mfma_f32_16x16x32_bf16(av, bv[ni], acc[mi][ni], 0, 0, 0);
      }
    }
    __syncthreads();
  }

#pragma unroll
  for (int mi = 0; mi < 4; mi++) {
#pragma unroll
    for (int r = 0; r < 4; r++) {
      int i = m0 + wm * 64 + mi * 16 + lquad * 4 + r;
      if (i >= M) continue;
#pragma unroll
      for (int ni = 0; ni < 4; ni++) {
        int j = n0 + wn * 64 + ni * 16 + lrow;
        if (j >= N) continue;
        Cb[(size_t)i * N + j] = f2bf(acc[mi][ni][r]);
      }
    }
  }
}

// ---------------------------------------------------------------------------
// K2: E = exp(ecorr * qcorr^T)  [1600x1600 per batch, K=256]
// Fused epilogue: E (coalesced 16B rows), ET (LDS transpose), Zrow/Zcol sums
// via shuffle + atomics.
// ---------------------------------------------------------------------------
__global__ __launch_bounds__(256) void gemm_corr_exp(
    const u16* __restrict__ A, const u16* __restrict__ B, u16* __restrict__ E,
    u16* __restrict__ ET, float* __restrict__ Zrow, float* __restrict__ Zcol) {
  __shared__ u16 lds_a[128 * 64];
  __shared__ u16 lds_b[128 * 64];
  int tid = threadIdx.x;
  int b = blockIdx.z;
  const u16* Ab = A + (size_t)b * 409600;
  const u16* Bb = B + (size_t)b * 409600;
  u16* Eb = E + (size_t)b * 2560000;
  u16* ETb = ET + (size_t)b * 2560000;
  int m0 = blockIdx.x * 128, n0 = blockIdx.y * 128;

  int rsub = tid >> 3;
  int gch = (tid & 7) ^ (rsub & 7);
  const char* pa[4];
  const char* pb[4];
#pragma unroll
  for (int c = 0; c < 4; c++) {
    int ra = m0 + 32 * c + rsub; ra = ra < 1600 ? ra : 1599;
    int rb = n0 + 32 * c + rsub; rb = rb < 1600 ? rb : 1599;
    pa[c] = (const char*)(Ab + (size_t)ra * 256) + gch * 16;
    pb[c] = (const char*)(Bb + (size_t)rb * 256) + gch * 16;
  }

  const f32x4 fzero = {0.f, 0.f, 0.f, 0.f};
  f32x4 acc[4][4];
#pragma unroll
  for (int mi = 0; mi < 4; mi++)
#pragma unroll
    for (int ni = 0; ni < 4; ni++) acc[mi][ni] = fzero;

  int wid = tid >> 6, lane = tid & 63;
  int wm = wid & 1, wn = wid >> 1;
  int lrow = lane & 15, lquad = lane >> 4;
  int sl = lrow & 7;

  for (int ks = 0; ks < 4; ks++) {
#pragma unroll
    for (int c = 0; c < 4; c++) {
      gll16(pa[c], (char*)lds_a + c * 4096 + tid * 16);
      gll16(pb[c], (char*)lds_b + c * 4096 + tid * 16);
      pa[c] += 128; pb[c] += 128;
    }
    __syncthreads();
#pragma unroll
    for (int k2 = 0; k2 < 2; k2++) {
      int sel = ((k2 << 2) | lquad) ^ sl;
      bf16x8 bv[4];
#pragma unroll
      for (int ni = 0; ni < 4; ni++) {
        int rowb = wn * 64 + ni * 16 + lrow;
        bv[ni] = *(const bf16x8*)((const char*)lds_b + rowb * 128 + sel * 16);
      }
#pragma unroll
      for (int mi = 0; mi < 4; mi++) {
        int rowa = wm * 64 + mi * 16 + lrow;
        bf16x8 av = *(const bf16x8*)((const char*)lds_a + rowa * 128 + sel * 16);
#pragma unroll
        for (int ni = 0; ni < 4; ni++)
          acc[mi][ni] =
              __builtin_amdgcn_mfma_f32_16x16x32_bf16(av, bv[ni], acc[mi][ni], 0, 0, 0);
      }
    }
    __syncthreads();
  }

  // ---- fused epilogue: exp, E store, ET store (LDS transpose), Z sums ----
  const int TS = 136;  // padded LDS row stride (u16) for 32x128 slice
  u16* T = lds_a;
  float colacc[4] = {0.f, 0.f, 0.f, 0.f};
#pragma unroll
  for (int s = 0; s < 4; s++) {
    if (wm == (s >> 1)) {
      int smi0 = (s & 1) * 2;
#pragma unroll
      for (int mi2 = 0; mi2 < 2; mi2++) {
        int mi = smi0 + mi2;
        float rowp[4] = {0.f, 0.f, 0.f, 0.f};
#pragma unroll
        for (int ni = 0; ni < 4; ni++) {
          int j = n0 + wn * 64 + ni * 16 + lrow;
          bool jv = j < 1600;
#pragma unroll
          for (int r = 0; r < 4; r++) {
            int i = m0 + wm * 64 + mi * 16 + lquad * 4 + r;
            float e = __expf(acc[mi][ni][r]);
            T[(mi2 * 16 + lquad * 4 + r) * TS + wn * 64 + ni * 16 + lrow] = f2bf(e);
            rowp[r] += jv ? e : 0.f;
            colacc[ni] += (i < 1600) ? e : 0.f;
          }
        }
#pragma unroll
        for (int r = 0; r < 4; r++) {
          float v = rowp[r];
          v += __shfl_xor(v, 1);
          v += __shfl_xor(v, 2);
          v += __shfl_xor(v, 4);
          v += __shfl_xor(v, 8);
          int i = m0 + wm * 64 + mi * 16 + lquad * 4 + r;
          if (lrow == 0 && i < 1600) atomicAdd(&Zrow[b * 1600 + i], v);
        }
      }
    }
    __syncthreads();
    // E rows: 32 rows x 128 cols, 16B coalesced stores
#pragma unroll
    for (int p = 0; p < 2; p++) {
      int jj = tid + p * 256;
      int ml = jj >> 4, n8 = jj & 15;
      int gi = m0 + s * 32 + ml, gj = n0 + n8 * 8;
      if (gi < 1600 && gj < 1600)
        *(uint4*)(Eb + (size_t)gi * 1600 + gj) = *(const uint4*)&T[ml * TS + n8 * 8];
    }
    // ET rows: transposed, 8B stores
#pragma unroll
    for (int p = 0; p < 4; p++) {
      int jj = tid + p * 256;
      int n = jj >> 3, m4 = jj & 7;
      int gm = m0 + s * 32 + m4 * 4, gn = n0 + n;
      if (gn < 1600 && gm < 1600) {
        ushort4 v;
        v.x = T[(m4 * 4 + 0) * TS + n];
        v.y = T[(m4 * 4 + 1) * TS + n];
        v.z = T[(m4 * 4 + 2) * TS + n];
        v.w = T[(m4 * 4 + 3) * TS + n];
        *(ushort4*)(ETb + (size_t)gn * 1600 + gm) = v;
      }
    }
    __syncthreads();
  }
#pragma unroll
  for (int ni = 0; ni < 4; ni++) {
    float v = colacc[ni];
    v += __shfl_xor(v, 16);
    v += __shfl_xor(v, 32);
    int j = n0 + wn * 64 + ni * 16 + lrow;
    if (lquad == 0 && j < 1600) atomicAdd(&Zcol[b * 1600 + j], v);
  }
}

// K3: out[idx] = bf16( x[idx] / Z[b][pixel] )   (both inputs via blockIdx.y)
__global__ void scale_div(const float* __restrict__ ex, const float* __restrict__ qu,
                          const float* __restrict__ Zcol, const float* __restrict__ Zrow,
                          u16* __restrict__ ebf, u16* __restrict__ qbf) {
  const float* x; const float* Z; u16* o;
  if (blockIdx.y == 0) { x = ex; Z = Zcol; o = ebf; }
  else { x = qu; Z = Zrow; o = qbf; }
  size_t idx = (size_t)blockIdx.x * 256 + threadIdx.x;  // 13,107,200
  int b = (int)(idx / 819200);
  int i = (int)(idx % 1600);
  o[idx] = f2bf(x[idx] / Z[b * 1600 + i]);
}

// ===========================================================================
// K4/K5: 128x128-tile, 256-thread (4 waves 2x2), 64KB LDS -> 2 blocks/CU so
// one block's vmcnt/barrier bubble is covered by the other block's MFMAs.
// 4-region rotation (region = BK=32 slice, [128 rows][32] u16 = 8KB/operand):
// stage@P -> R[(P+2)%4] (4 x gll16), frag-RD@P -> R[(P+1)%4], MFMA@P
// consumes frags read @P-1. Single barrier + counted vmcnt(4) per phase
// (waits prev stage only; own stage stays in flight) -- r5-proven schedule.
// Bijective chunked XCD swizzle (1664 blocks, 1664%8==0) keeps each batch's
// A/B panels XCD-local.
// ===========================================================================

// ---------------------------------------------------------------------------
// K4: att GEMMs. A = proj (512x1600 K-major), B = E/ET rows, C -> padded
// pixel layout bf16. K = 1600 = 50 phases: 12 iters + 2-phase tail.
// ---------------------------------------------------------------------------
__global__ __launch_bounds__(256, 2) void att_gemm128(
    const u16* __restrict__ Aw1, const u16* __restrict__ Bp1, u16* __restrict__ C1,
    const u16* __restrict__ Aw2, const u16* __restrict__ Bp2, u16* __restrict__ C2) {
  __shared__ u16 ldsA[16384];  // [4 regions][128 rows][32 elems]
  __shared__ u16 ldsB[16384];
  int tid = threadIdx.x;
  int flat = blockIdx.x + blockIdx.y * 13 + blockIdx.z * 52;  // 13x4x32 = 1664
  int wrk = (flat & 7) * 208 + (flat >> 3);                   // chunked XCD swizzle
  int z = wrk / 52;
  int r2 = wrk - z * 52;
  int by = r2 / 13, bx = r2 - by * 13;
  int b = z & 15;
  const u16* Aw = (z < 16 ? Aw1 : Aw2) + (size_t)b * 819200;
  const u16* Bp = (z < 16 ? Bp1 : Bp2) + (size_t)b * 2560000;
  u16* Cb = (z < 16 ? C1 : C2) + (size_t)b * 903168;
  int p0 = bx * 128, c0 = by * 128;

  // ---- staging setup: 4 x gll16 per region; rows 0..63 / 64..127 ----
  int rl = tid >> 2;                      // 0..63
  int cs = (tid & 3) ^ ((rl >> 1) & 3);   // swizzled 16B source chunk (of 4)
  const char* pA0 = (const char*)(Aw + (size_t)(c0 + rl) * 1600) + cs * 16;
  const char* pA1 = pA0 + 64 * 3200;
  int pp0 = p0 + rl; pp0 = pp0 < 1600 ? pp0 : 1599;
  const char* pB0 = (const char*)(Bp + (size_t)pp0 * 1600) + cs * 16;
  int pp1 = p0 + 64 + rl; pp1 = pp1 < 1600 ? pp1 : 1599;
  const char* pB1 = (const char*)(Bp + (size_t)pp1 * 1600) + cs * 16;

  char* ldsAb = (char*)ldsA;
  char* ldsBb = (char*)ldsB;
  int dstT = tid * 16;

#define STAGE_U(d, kh, ks)                                              \
  {                                                                     \
    int ko = (ks) * 64;                                                 \
    int ro = ((d) * 2 + (kh)) * 8192;                                   \
    gll16(pA0 + ko, ldsAb + ro + dstT);                                 \
    gll16(pA1 + ko, ldsAb + ro + 4096 + dstT);                          \
    gll16(pB0 + ko, ldsBb + ro + dstT);                                 \
    gll16(pB1 + ko, ldsBb + ro + 4096 + dstT);                          \
  }

  // ---- compute-side lane mapping: 4 waves, 2(c) x 2(p), wave tile 64x64 ----
  int wid = tid >> 6, lane = tid & 63;
  int wm = wid & 1, wn = wid >> 1;
  int lrow = lane & 15, lquad = lane >> 4;
  int csel = (lquad ^ ((lrow >> 1) & 3)) << 4;
  int aBase = (wm * 64 + lrow) * 64 + csel;
  int bBase = (wn * 64 + lrow) * 64 + csel;

  const f32x4 fzero = {0.f, 0.f, 0.f, 0.f};
  f32x4 acc[4][4];
#pragma unroll
  for (int mi = 0; mi < 4; mi++)
#pragma unroll
    for (int ni = 0; ni < 4; ni++) acc[mi][ni] = fzero;

  bf16x8 fa0, fa1, fa2, fa3, fb0, fb1, fb2, fb3;
  bf16x8 ga0, ga1, ga2, ga3, gb0, gb1, gb2, gb3;

#define RD(pre, d, kh)                                                  \
  {                                                                     \
    const char* ra_ = ldsAb + ((d) * 2 + (kh)) * 8192 + aBase;          \
    const char* rb_ = ldsBb + ((d) * 2 + (kh)) * 8192 + bBase;          \
    pre##a0 = *(const bf16x8*)(ra_);                                    \
    pre##a1 = *(const bf16x8*)(ra_ + 1024);                             \
    pre##a2 = *(const bf16x8*)(ra_ + 2048);                             \
    pre##a3 = *(const bf16x8*)(ra_ + 3072);                             \
    pre##b0 = *(const bf16x8*)(rb_);                                    \
    pre##b1 = *(const bf16x8*)(rb_ + 1024);                             \
    pre##b2 = *(const bf16x8*)(rb_ + 2048);                             \
    pre##b3 = *(const bf16x8*)(rb_ + 3072);                             \
  }

#define MROW(mi, av, pre)                                                               \
  acc[mi][0] = __builtin_amdgcn_mfma_f32_16x16x32_bf16(av, pre##b0, acc[mi][0], 0, 0, 0); \
  acc[mi][1] = __builtin_amdgcn_mfma_f32_16x16x32_bf16(av, pre##b1, acc[mi][1], 0, 0, 0); \
  acc[mi][2] = __builtin_amdgcn_mfma_f32_16x16x32_bf16(av, pre##b2, acc[mi][2], 0, 0, 0); \
  acc[mi][3] = __builtin_amdgcn_mfma_f32_16x16x32_bf16(av, pre##b3, acc[mi][3], 0, 0, 0);

#define MALL(pre)                                                              \
  MROW(0, pre##a0, pre) MROW(1, pre##a1, pre) MROW(2, pre##a2, pre) MROW(3, pre##a3, pre)

#define PHASE(rd_d, rd_kh, rdp, cp, STG)                                       \
  {                                                                            \
    STG;                                                                       \
    asm volatile("s_waitcnt vmcnt(4)" ::: "memory");                           \
    __builtin_amdgcn_s_barrier();                                              \
    RD(rdp, rd_d, rd_kh);                                                      \
    __builtin_amdgcn_s_setprio(1);                                             \
    MALL(cp)                                                                   \
    __builtin_amdgcn_s_setprio(0);                                             \
  }

  // ---- prologue: R0<-ks0, R1<-ks1; F <- R0 ----
  STAGE_U(0, 0, 0);
  STAGE_U(0, 1, 1);
  asm volatile("s_waitcnt vmcnt(4)" ::: "memory");  // R0 landed
  __builtin_amdgcn_s_barrier();
  RD(f, 0, 0);

#pragma unroll 1
  for (int it = 0; it < 12; ++it) {
    int k2 = it * 4 + 2, k3 = it * 4 + 3, k4 = it * 4 + 4, k5 = it * 4 + 5;  // <= 49
    PHASE(0, 1, g, f, STAGE_U(1, 0, k2));  // P=4it+0: mfma ks, read R1
    PHASE(1, 0, f, g, STAGE_U(1, 1, k3));  // P+1
    PHASE(1, 1, g, f, STAGE_U(0, 0, k4));  // P+2
    PHASE(0, 0, f, g, STAGE_U(0, 1, k5));  // P+3
  }
  // ---- tail: ks48 in R0 (f holds frags), ks49 in R1 ----
  asm volatile("s_waitcnt vmcnt(0)" ::: "memory");
  __builtin_amdgcn_s_barrier();
  RD(g, 0, 1);
  __builtin_amdgcn_s_setprio(1);
  MALL(f)
  MALL(g)
  __builtin_amdgcn_s_setprio(0);

#undef PHASE
#undef MALL
#undef MROW
#undef RD
#undef STAGE_U

  // ---- epilogue: bf16 stores to padded pixel layout ----
#pragma unroll
  for (int mi = 0; mi < 4; mi++) {
#pragma unroll
    for (int r = 0; r < 4; r++) {
      int o = c0 + wm * 64 + mi * 16 + lquad * 4 + r;
#pragma unroll
      for (int ni = 0; ni < 4; ni++) {
        int p = p0 + wn * 64 + ni * 16 + lrow;
        if (p < 1600) {
          int y = p / 40, x = p - y * 40;
          Cb[(size_t)((y + 1) * 42 + (x + 1)) * 512 + o] = f2bf(acc[mi][ni][r]);
        }
      }
    }
  }
}

// ---------------------------------------------------------------------------
// K5: both 3x3 convs. A = repacked W (512x4608, k=t*512+c), B = padded att
// pixel rows. K = 4608 = 144 phases exactly (36 iters). out fp32.
// ---------------------------------------------------------------------------
__global__ __launch_bounds__(256, 2) void conv_gemm128(
    const u16* __restrict__ W1, const u16* __restrict__ ATT1,
    const u16* __restrict__ W2, const u16* __restrict__ ATT2,
    float* __restrict__ out) {
  __shared__ u16 ldsA[16384];
  __shared__ u16 ldsB[16384];
  int tid = threadIdx.x;
  int flat = blockIdx.x + blockIdx.y * 13 + blockIdx.z * 52;  // 1664 blocks
  int wrk = (flat & 7) * 208 + (flat >> 3);
  int z = wrk / 52;
  int r2 = wrk - z * 52;
  int by = r2 / 13, bx = r2 - by * 13;
  int b = z & 15, sel2 = z >> 4;
  const u16* W = sel2 ? W2 : W1;
  const u16* attb = (sel2 ? ATT2 : ATT1) + (size_t)b * 903168;
  float* outb = out + (size_t)b * 1638400 + (size_t)(sel2 ? 512 : 0) * 1600;
  int p0 = bx * 128, o0 = by * 128;

  int rl = tid >> 2;                      // 0..63
  int cs = (tid & 3) ^ ((rl >> 1) & 3);
  const char* pA0 = (const char*)(W + (size_t)(o0 + rl) * 4608) + cs * 16;
  const char* pA1 = pA0 + 64 * 9216;
  int pp0 = p0 + rl; pp0 = pp0 < 1600 ? pp0 : 1599;
  int y0 = pp0 / 40, x0 = pp0 - y0 * 40;
  const char* pB0 = (const char*)(attb + (size_t)(y0 * 42 + x0) * 512) + cs * 16;
  int pp1 = p0 + 64 + rl; pp1 = pp1 < 1600 ? pp1 : 1599;
  int y1 = pp1 / 40, x1 = pp1 - y1 * 40;
  const char* pB1 = (const char*)(attb + (size_t)(y1 * 42 + x1) * 512) + cs * 16;

  char* ldsAb = (char*)ldsA;
  char* ldsBb = (char*)ldsB;
  int dstT = tid * 16;

#define STAGE_U(d, kh, ks)                                              \
  {                                                                     \
    int koA = (ks) * 64;                                                \
    int tp = (ks) >> 4;                                                 \
    int ty = (tp * 11) >> 5;                                            \
    int tx = tp - ty * 3;                                               \
    int koB = (ty * 42 + tx) * 1024 + ((ks) & 15) * 64;                 \
    int ro = ((d) * 2 + (kh)) * 8192;                                   \
    gll16(pA0 + koA, ldsAb + ro + dstT);                                \
    gll16(pA1 + koA, ldsAb + ro + 4096 + dstT);                         \
    gll16(pB0 + koB, ldsBb + ro + dstT);                                \
    gll16(pB1 + koB, ldsBb + ro + 4096 + dstT);                         \
  }

  int wid = tid >> 6, lane = tid & 63;
  int wm = wid & 1, wn = wid >> 1;
  int lrow = lane & 15, lquad = lane >> 4;
  int csel = (lquad ^ ((lrow >> 1) & 3)) << 4;
  int aBase = (wm * 64 + lrow) * 64 + csel;
  int bBase = (wn * 64 + lrow) * 64 + csel;

  const f32x4 fzero = {0.f, 0.f, 0.f, 0.f};
  f32x4 acc[4][4];
#pragma unroll
  for (int mi = 0; mi < 4; mi++)
#pragma unroll
    for (int ni = 0; ni < 4; ni++) acc[mi][ni] = fzero;

  bf16x8 fa0, fa1, fa2, fa3, fb0, fb1, fb2, fb3;
  bf16x8 ga0, ga1, ga2, ga3, gb0, gb1, gb2, gb3;

#define RD(pre, d, kh)                                                  \
  {                                                                     \
    const char* ra_ = ldsAb + ((d) * 2 + (kh)) * 8192 + aBase;          \
    const char* rb_ = ldsBb + ((d) * 2 + (kh)) * 8192 + bBase;          \
    pre##a0 = *(const bf16x8*)(ra_);                                    \
    pre##a1 = *(const bf16x8*)(ra_ + 1024);                             \
    pre##a2 = *(const bf16x8*)(ra_ + 2048);                             \
    pre##a3 = *(const bf16x8*)(ra_ + 3072);                             \
    pre##b0 = *(const bf16x8*)(rb_);                                    \
    pre##b1 = *(const bf16x8*)(rb_ + 1024);                             \
    pre##b2 = *(const bf16x8*)(rb_ + 2048);                             \
    pre##b3 = *(const bf16x8*)(rb_ + 3072);                             \
  }

#define MROW(mi, av, pre)                                                               \
  acc[mi][0] = __builtin_amdgcn_mfma_f32_16x16x32_bf16(av, pre##b0, acc[mi][0], 0, 0, 0); \
  acc[mi][1] = __builtin_amdgcn_mfma_f32_16x16x32_bf16(av, pre##b1, acc[mi][1], 0, 0, 0); \
  acc[mi][2] = __builtin_amdgcn_mfma_f32_16x16x32_bf16(av, pre##b2, acc[mi][2], 0, 0, 0); \
  acc[mi][3] = __builtin_amdgcn_mfma_f32_16x16x32_bf16(av, pre##b3, acc[mi][3], 0, 0, 0);

#define MALL(pre)                                                              \
  MROW(0, pre##a0, pre) MROW(1, pre##a1, pre) MROW(2, pre##a2, pre) MROW(3, pre##a3, pre)

#define PHASE(rd_d, rd_kh, rdp, cp, STG)                                       \
  {                                                                            \
    STG;                                                                       \
    asm volatile("s_waitcnt vmcnt(4)" ::: "memory");                           \
    __builtin_amdgcn_s_barrier();                                              \
    RD(rdp, rd_d, rd_kh);                                                      \
    __builtin_amdgcn_s_setprio(1);                                             \
    MALL(cp)                                                                   \
    __builtin_amdgcn_s_setprio(0);                                             \
  }

  // ---- prologue: R0<-ks0, R1<-ks1; F <- R0 ----
  STAGE_U(0, 0, 0);
  STAGE_U(0, 1, 1);
  asm volatile("s_waitcnt vmcnt(4)" ::: "memory");
  __builtin_amdgcn_s_barrier();
  RD(f, 0, 0);

#pragma unroll 1
  for (int it = 0; it < 36; ++it) {
    int k2 = it * 4 + 2, k3 = it * 4 + 3;
    int k4 = it * 4 + 4; k4 = k4 < 144 ? k4 : 143;  // dup on last iter, unread
    int k5 = it * 4 + 5; k5 = k5 < 144 ? k5 : 143;
    PHASE(0, 1, g, f, STAGE_U(1, 0, k2));
    PHASE(1, 0, f, g, STAGE_U(1, 1, k3));
    PHASE(1, 1, g, f, STAGE_U(0, 0, k4));
    PHASE(0, 0, f, g, STAGE_U(0, 1, k5));
  }

#undef PHASE
#undef MALL
#undef MROW
#undef RD
#undef STAGE_U

  // ---- epilogue: fp32 stores, guard pixel tail ----
#pragma unroll
  for (int mi = 0; mi < 4; mi++) {
#pragma unroll
    for (int r = 0; r < 4; r++) {
      int o = o0 + wm * 64 + mi * 16 + lquad * 4 + r;
      float* orow = outb + (size_t)o * 1600;
#pragma unroll
      for (int ni = 0; ni < 4; ni++) {
        int p = p0 + wn * 64 + ni * 16 + lrow;
        if (p < 1600) orow[p] = acc[mi][ni][r];
      }
    }
  }
}

// ---------------------------------------------------------------------------
extern "C" void kernel_launch(void* const* d_in, const int* in_sizes, int n_in,
                              void* d_out, int out_size, void* d_ws, size_t ws_size,
                              hipStream_t stream) {
  const float* ex = (const float*)d_in[0];
  const float* qu = (const float*)d_in[1];
  const float* w_e = (const float*)d_in[2];
  const float* w_q = (const float*)d_in[3];
  const float* w_c1 = (const float*)d_in[4];
  const float* w_c2 = (const float*)d_in[5];
  float* out = (float*)d_out;
  char* ws = (char*)d_ws;

  u16* E     = (u16*)(ws + 0L);            // 81,920,000
  u16* ET    = (u16*)(ws + 81920000L);     // 81,920,000
  u16* xt_e  = (u16*)(ws + 163840000L);    // 26,214,400 (reused as ebf)
  u16* xt_q  = (u16*)(ws + 190054400L);    // 26,214,400 (reused as qbf)
  u16* ecorr = (u16*)(ws + 216268800L);    // 13,107,200
  u16* qcorr = (u16*)(ws + 229376000L);    // 13,107,200
  u16* att_e = (u16*)(ws + 242483200L);    // 28,901,376
  u16* att_q = (u16*)(ws + 271384576L);    // 28,901,376
  float* Zrow = (float*)(ws + 300285952L); // 102,400
  float* Zcol = (float*)(ws + 300388352L); // 102,400
  u16* w_ebf = (u16*)(ws + 300490752L);    // 262,144
  u16* w_qbf = (u16*)(ws + 300752896L);    // 262,144
  u16* wr1   = (u16*)(ws + 301015040L);    // 4,718,592
  u16* wr2   = (u16*)(ws + 305733632L);    // 4,718,592  (total 310,452,224)

  // prep
  transp_cast_x2<<<dim3(50, 16, 32), 256, 0, stream>>>(ex, qu, xt_e, xt_q);
  cast_w<<<dim3(512), 256, 0, stream>>>(w_e, w_q, w_ebf, w_qbf);
  repack_wc<<<dim3(9216, 2), 256, 0, stream>>>(w_c1, w_c2, wr1, wr2);
  // zero att_e, att_q, Zrow, Zcol (contiguous): 58,007,552 B
  zero_mem<<<dim3(2048), 256, 0, stream>>>((uint4*)att_e, 3625472L);

  // K1: corr[b][n][o] = sum_c xt[n,c] * w[o,c]   (both e and q in one grid)
  gemm_bt64<0><<<dim3(13, 2, 32), 256, 0, stream>>>(
      xt_e, w_ebf, ecorr, xt_q, w_qbf, qcorr, 1600, 256, 512, 819200L, 0L, 409600L);

  // K2: E/ET/Zrow/Zcol fused
  gemm_corr_exp<<<dim3(13, 13, 16), 256, 0, stream>>>(ecorr, qcorr, E, ET, Zrow, Zcol);

  // K3: scale inputs by softmax denominators
  u16* ebf = xt_e;
  u16* qbf = xt_q;
  scale_div<<<dim3(51200, 2), 256, 0, stream>>>(ex, qu, Zcol, Zrow, ebf, qbf);

  // K4: att_q[p][c] = sum_i E[p,i]*ebf[c,i] ; att_e[p][c] = sum_i ET[p,i]*qbf[c,i]
  att_gemm128<<<dim3(13, 4, 32), 256, 0, stream>>>(ebf, E, att_q, qbf, ET, att_e);

  // K5: both convs, 128x128 2-blocks/CU
  conv_gemm128<<<dim3(13, 4, 32), 256, 0, stream>>>(wr1, att_e, wr2, att_q, out);
}

// Round 8
// 796.060 us; speedup vs baseline: 1.1085x; 1.1085x over previous
//
#include <hip/hip_runtime.h>

typedef unsigned short u16;
typedef __attribute__((ext_vector_type(8))) short bf16x8;
typedef __attribute__((ext_vector_type(4))) float f32x4;

__device__ __forceinline__ u16 f2bf(float f) {
  union { float f; unsigned u; } v; v.f = f;
  unsigned u = v.u;
  u += 0x7fffu + ((u >> 16) & 1u);
  return (u16)(u >> 16);
}

__device__ __forceinline__ void gll16(const void* g, void* l) {
  __builtin_amdgcn_global_load_lds(
      (const __attribute__((address_space(1))) void*)g,
      (__attribute__((address_space(3))) void*)l, 16, 0, 0);
}

// ---------------------------------------------------------------------------
// P1: x[b][c][n] f32 -> xt[b][n][c] bf16   (C=512, N=1600), both inputs
// ---------------------------------------------------------------------------
__global__ __launch_bounds__(256) void transp_cast_x2(const float* __restrict__ ex,
                                                      const float* __restrict__ qu,
                                                      u16* __restrict__ xte,
                                                      u16* __restrict__ xtq) {
  __shared__ float t[32][33];
  int z = blockIdx.z;
  int b = z & 15;
  const float* xb = (z < 16 ? ex : qu) + (size_t)b * 819200;
  u16* xtb = (z < 16 ? xte : xtq) + (size_t)b * 819200;
  int n0 = blockIdx.x * 32, c0 = blockIdx.y * 32;
  int tx = threadIdx.x & 31, ty = threadIdx.x >> 5;
#pragma unroll
  for (int k = 0; k < 4; k++) {
    int c = ty + k * 8;
    t[c][tx] = xb[(size_t)(c0 + c) * 1600 + n0 + tx];
  }
  __syncthreads();
#pragma unroll
  for (int k = 0; k < 4; k++) {
    int n = ty + k * 8;
    xtb[(size_t)(n0 + n) * 512 + c0 + tx] = f2bf(t[tx][n]);
  }
}

// P2: cast w_e / w_q (256x512 each) to bf16
__global__ void cast_w(const float* __restrict__ we, const float* __restrict__ wq,
                       u16* __restrict__ oe, u16* __restrict__ oq) {
  int i = blockIdx.x * 256 + threadIdx.x;
  oe[i] = f2bf(we[i]);
  oq[i] = f2bf(wq[i]);
}

// P3: w[o][c][ky][kx] f32 -> wr[o][t*512+c] bf16 (both conv weights)
__global__ void repack_wc(const float* __restrict__ w1, const float* __restrict__ w2,
                          u16* __restrict__ o1, u16* __restrict__ o2) {
  const float* w = blockIdx.y ? w2 : w1;
  u16* wr = blockIdx.y ? o2 : o1;
  int idx = blockIdx.x * 256 + threadIdx.x;  // 2359296 total
  int o = idx / 4608;
  int r = idx - o * 4608;
  int t = r >> 9;
  int c = r & 511;
  wr[idx] = f2bf(w[o * 4608 + c * 9 + t]);
}

// P4: zero only the pad RING of att buffers (164 pixels x 512 ch x 32 bufs)
// + Zrow/Zcol. K4 writes all interior pixels, so full-buffer zero is waste.
__global__ void zero_pad(u16* __restrict__ att, float* __restrict__ Z) {
  int q = blockIdx.x;
  uint4 zz; zz.x = 0; zz.y = 0; zz.z = 0; zz.w = 0;
  if (q < 32) {
    uint4* base = (uint4*)(att + (size_t)q * 903168);
    for (int i = threadIdx.x; i < 10496; i += 256) {  // 164 px * 64 uint4
      int t = i >> 6, c = i & 63;
      int y, x;
      if (t < 42) { y = 0; x = t; }
      else if (t < 84) { y = 41; x = t - 42; }
      else if (t < 124) { y = 1 + (t - 84); x = 0; }
      else { y = 1 + (t - 124); x = 41; }
      base[(y * 42 + x) * 64 + c] = zz;
    }
  } else {
    uint4* p = (uint4*)Z;  // Zrow+Zcol contiguous: 204800 B = 12800 uint4
    for (int i = threadIdx.x; i < 12800; i += 256) p[i] = zz;
  }
}

// ===========================================================================
// Small-K GEMM template (K1, K2, K4): 128x128 tile, 256 thr (4 waves 2x2),
// 64KB LDS -> 2 blocks/CU; 4-region rotation (region = BK=32 slice), frag
// prefetch, single barrier + counted vmcnt(4) per phase. Proven r7 (K4 -13us).
// ===========================================================================

// ---------------------------------------------------------------------------
// K1: corr[n][o] = sum_c xt[n,c]*w[o,c].  M=1600, N=256, K=512 (16 phases).
// ---------------------------------------------------------------------------
__global__ __launch_bounds__(256, 2) void corr_gemm128(
    const u16* __restrict__ X1, const u16* __restrict__ Wg1, u16* __restrict__ C1,
    const u16* __restrict__ X2, const u16* __restrict__ Wg2, u16* __restrict__ C2) {
  __shared__ u16 ldsA[16384];
  __shared__ u16 ldsB[16384];
  int tid = threadIdx.x;
  int flat = blockIdx.x + blockIdx.y * 13 + blockIdx.z * 26;  // 832 blocks
  int wrk = (flat & 7) * 104 + (flat >> 3);
  int z = wrk / 26;
  int r2 = wrk - z * 26;
  int by = r2 / 13, bx = r2 - by * 13;
  int b = z & 15;
  const u16* A = (z < 16 ? X1 : X2) + (size_t)b * 819200;
  const u16* B = (z < 16 ? Wg1 : Wg2);
  u16* Cb = (z < 16 ? C1 : C2) + (size_t)b * 409600;
  int m0 = bx * 128, n0 = by * 128;

  int rl = tid >> 2;
  int cs = (tid & 3) ^ ((rl >> 1) & 3);
  int ra0 = m0 + rl; ra0 = ra0 < 1600 ? ra0 : 1599;
  int ra1 = m0 + 64 + rl; ra1 = ra1 < 1600 ? ra1 : 1599;
  const char* pA0 = (const char*)(A + (size_t)ra0 * 512) + cs * 16;
  const char* pA1 = (const char*)(A + (size_t)ra1 * 512) + cs * 16;
  const char* pB0 = (const char*)(B + (size_t)(n0 + rl) * 512) + cs * 16;
  const char* pB1 = (const char*)(B + (size_t)(n0 + 64 + rl) * 512) + cs * 16;

  char* ldsAb = (char*)ldsA;
  char* ldsBb = (char*)ldsB;
  int dstT = tid * 16;

#define STAGE_U(d, kh, ks)                                              \
  {                                                                     \
    int ko = (ks) * 64;                                                 \
    int ro = ((d) * 2 + (kh)) * 8192;                                   \
    gll16(pA0 + ko, ldsAb + ro + dstT);                                 \
    gll16(pA1 + ko, ldsAb + ro + 4096 + dstT);                          \
    gll16(pB0 + ko, ldsBb + ro + dstT);                                 \
    gll16(pB1 + ko, ldsBb + ro + 4096 + dstT);                          \
  }

  int wid = tid >> 6, lane = tid & 63;
  int wm = wid & 1, wn = wid >> 1;
  int lrow = lane & 15, lquad = lane >> 4;
  int csel = (lquad ^ ((lrow >> 1) & 3)) << 4;
  int aBase = (wm * 64 + lrow) * 64 + csel;
  int bBase = (wn * 64 + lrow) * 64 + csel;

  const f32x4 fzero = {0.f, 0.f, 0.f, 0.f};
  f32x4 acc[4][4];
#pragma unroll
  for (int mi = 0; mi < 4; mi++)
#pragma unroll
    for (int ni = 0; ni < 4; ni++) acc[mi][ni] = fzero;

  bf16x8 fa0, fa1, fa2, fa3, fb0, fb1, fb2, fb3;
  bf16x8 ga0, ga1, ga2, ga3, gb0, gb1, gb2, gb3;

#define RD(pre, d, kh)                                                  \
  {                                                                     \
    const char* ra_ = ldsAb + ((d) * 2 + (kh)) * 8192 + aBase;          \
    const char* rb_ = ldsBb + ((d) * 2 + (kh)) * 8192 + bBase;          \
    pre##a0 = *(const bf16x8*)(ra_);                                    \
    pre##a1 = *(const bf16x8*)(ra_ + 1024);                             \
    pre##a2 = *(const bf16x8*)(ra_ + 2048);                             \
    pre##a3 = *(const bf16x8*)(ra_ + 3072);                             \
    pre##b0 = *(const bf16x8*)(rb_);                                    \
    pre##b1 = *(const bf16x8*)(rb_ + 1024);                             \
    pre##b2 = *(const bf16x8*)(rb_ + 2048);                             \
    pre##b3 = *(const bf16x8*)(rb_ + 3072);                             \
  }

#define MROW(mi, av, pre)                                                               \
  acc[mi][0] = __builtin_amdgcn_mfma_f32_16x16x32_bf16(av, pre##b0, acc[mi][0], 0, 0, 0); \
  acc[mi][1] = __builtin_amdgcn_mfma_f32_16x16x32_bf16(av, pre##b1, acc[mi][1], 0, 0, 0); \
  acc[mi][2] = __builtin_amdgcn_mfma_f32_16x16x32_bf16(av, pre##b2, acc[mi][2], 0, 0, 0); \
  acc[mi][3] = __builtin_amdgcn_mfma_f32_16x16x32_bf16(av, pre##b3, acc[mi][3], 0, 0, 0);

#define MALL(pre)                                                              \
  MROW(0, pre##a0, pre) MROW(1, pre##a1, pre) MROW(2, pre##a2, pre) MROW(3, pre##a3, pre)

#define PHASE(rd_d, rd_kh, rdp, cp, STG)                                       \
  {                                                                            \
    STG;                                                                       \
    asm volatile("s_waitcnt vmcnt(4)" ::: "memory");                           \
    __builtin_amdgcn_s_barrier();                                              \
    RD(rdp, rd_d, rd_kh);                                                      \
    __builtin_amdgcn_s_setprio(1);                                             \
    MALL(cp)                                                                   \
    __builtin_amdgcn_s_setprio(0);                                             \
  }

  STAGE_U(0, 0, 0);
  STAGE_U(0, 1, 1);
  asm volatile("s_waitcnt vmcnt(4)" ::: "memory");
  __builtin_amdgcn_s_barrier();
  RD(f, 0, 0);

#pragma unroll 1
  for (int it = 0; it < 4; ++it) {
    int k2 = it * 4 + 2, k3 = it * 4 + 3;
    int k4 = it * 4 + 4; k4 = k4 < 16 ? k4 : 15;  // dead dup on last iter
    int k5 = it * 4 + 5; k5 = k5 < 16 ? k5 : 15;
    PHASE(0, 1, g, f, STAGE_U(1, 0, k2));
    PHASE(1, 0, f, g, STAGE_U(1, 1, k3));
    PHASE(1, 1, g, f, STAGE_U(0, 0, k4));
    PHASE(0, 0, f, g, STAGE_U(0, 1, k5));
  }

#undef PHASE
#undef MALL
#undef MROW
#undef RD
#undef STAGE_U

#pragma unroll
  for (int mi = 0; mi < 4; mi++) {
#pragma unroll
    for (int r = 0; r < 4; r++) {
      int i = m0 + wm * 64 + mi * 16 + lquad * 4 + r;
      if (i >= 1600) continue;
#pragma unroll
      for (int ni = 0; ni < 4; ni++) {
        int j = n0 + wn * 64 + ni * 16 + lrow;
        Cb[(size_t)i * 256 + j] = f2bf(acc[mi][ni][r]);
      }
    }
  }
}

// ---------------------------------------------------------------------------
// K2: E = exp(ecorr * qcorr^T)  [1600x1600 per batch, K=256 -> 8 phases].
// Main loop = 128^2 prefetch template (64KB LDS, 2 blocks/CU); fused
// epilogue (E rows, ET transpose via LDS, Zrow/Zcol shuffle+atomics)
// unchanged from the proven kernel (identical wave/acc layout).
// ---------------------------------------------------------------------------
__global__ __launch_bounds__(256, 2) void corr_exp128(
    const u16* __restrict__ A, const u16* __restrict__ B, u16* __restrict__ E,
    u16* __restrict__ ET, float* __restrict__ Zrow, float* __restrict__ Zcol) {
  __shared__ u16 ldsA[16384];
  __shared__ u16 ldsB[16384];
  int tid = threadIdx.x;
  int flat = blockIdx.x + blockIdx.y * 13 + blockIdx.z * 169;  // 2704 blocks
  int wrk = (flat & 7) * 338 + (flat >> 3);
  int b = wrk / 169;
  int r2 = wrk - b * 169;
  int by = r2 / 13, bx = r2 - by * 13;
  const u16* Ab = A + (size_t)b * 409600;
  const u16* Bb = B + (size_t)b * 409600;
  u16* Eb = E + (size_t)b * 2560000;
  u16* ETb = ET + (size_t)b * 2560000;
  int m0 = bx * 128, n0 = by * 128;

  int rl = tid >> 2;
  int cs = (tid & 3) ^ ((rl >> 1) & 3);
  int ra0 = m0 + rl; ra0 = ra0 < 1600 ? ra0 : 1599;
  int ra1 = m0 + 64 + rl; ra1 = ra1 < 1600 ? ra1 : 1599;
  int rb0 = n0 + rl; rb0 = rb0 < 1600 ? rb0 : 1599;
  int rb1 = n0 + 64 + rl; rb1 = rb1 < 1600 ? rb1 : 1599;
  const char* pA0 = (const char*)(Ab + (size_t)ra0 * 256) + cs * 16;
  const char* pA1 = (const char*)(Ab + (size_t)ra1 * 256) + cs * 16;
  const char* pB0 = (const char*)(Bb + (size_t)rb0 * 256) + cs * 16;
  const char* pB1 = (const char*)(Bb + (size_t)rb1 * 256) + cs * 16;

  char* ldsAb = (char*)ldsA;
  char* ldsBb = (char*)ldsB;
  int dstT = tid * 16;

#define STAGE_U(d, kh, ks)                                              \
  {                                                                     \
    int ko = (ks) * 64;                                                 \
    int ro = ((d) * 2 + (kh)) * 8192;                                   \
    gll16(pA0 + ko, ldsAb + ro + dstT);                                 \
    gll16(pA1 + ko, ldsAb + ro + 4096 + dstT);                          \
    gll16(pB0 + ko, ldsBb + ro + dstT);                                 \
    gll16(pB1 + ko, ldsBb + ro + 4096 + dstT);                          \
  }

  int wid = tid >> 6, lane = tid & 63;
  int wm = wid & 1, wn = wid >> 1;
  int lrow = lane & 15, lquad = lane >> 4;
  int csel = (lquad ^ ((lrow >> 1) & 3)) << 4;
  int aBase = (wm * 64 + lrow) * 64 + csel;
  int bBase = (wn * 64 + lrow) * 64 + csel;

  const f32x4 fzero = {0.f, 0.f, 0.f, 0.f};
  f32x4 acc[4][4];
#pragma unroll
  for (int mi = 0; mi < 4; mi++)
#pragma unroll
    for (int ni = 0; ni < 4; ni++) acc[mi][ni] = fzero;

  bf16x8 fa0, fa1, fa2, fa3, fb0, fb1, fb2, fb3;
  bf16x8 ga0, ga1, ga2, ga3, gb0, gb1, gb2, gb3;

#define RD(pre, d, kh)                                                  \
  {                                                                     \
    const char* ra_ = ldsAb + ((d) * 2 + (kh)) * 8192 + aBase;          \
    const char* rb_ = ldsBb + ((d) * 2 + (kh)) * 8192 + bBase;          \
    pre##a0 = *(const bf16x8*)(ra_);                                    \
    pre##a1 = *(const bf16x8*)(ra_ + 1024);                             \
    pre##a2 = *(const bf16x8*)(ra_ + 2048);                             \
    pre##a3 = *(const bf16x8*)(ra_ + 3072);                             \
    pre##b0 = *(const bf16x8*)(rb_);                                    \
    pre##b1 = *(const bf16x8*)(rb_ + 1024);                             \
    pre##b2 = *(const bf16x8*)(rb_ + 2048);                             \
    pre##b3 = *(const bf16x8*)(rb_ + 3072);                             \
  }

#define MROW(mi, av, pre)                                                               \
  acc[mi][0] = __builtin_amdgcn_mfma_f32_16x16x32_bf16(av, pre##b0, acc[mi][0], 0, 0, 0); \
  acc[mi][1] = __builtin_amdgcn_mfma_f32_16x16x32_bf16(av, pre##b1, acc[mi][1], 0, 0, 0); \
  acc[mi][2] = __builtin_amdgcn_mfma_f32_16x16x32_bf16(av, pre##b2, acc[mi][2], 0, 0, 0); \
  acc[mi][3] = __builtin_amdgcn_mfma_f32_16x16x32_bf16(av, pre##b3, acc[mi][3], 0, 0, 0);

#define MALL(pre)                                                              \
  MROW(0, pre##a0, pre) MROW(1, pre##a1, pre) MROW(2, pre##a2, pre) MROW(3, pre##a3, pre)

#define PHASE(rd_d, rd_kh, rdp, cp, STG)                                       \
  {                                                                            \
    STG;                                                                       \
    asm volatile("s_waitcnt vmcnt(4)" ::: "memory");                           \
    __builtin_amdgcn_s_barrier();                                              \
    RD(rdp, rd_d, rd_kh);                                                      \
    __builtin_amdgcn_s_setprio(1);                                             \
    MALL(cp)                                                                   \
    __builtin_amdgcn_s_setprio(0);                                             \
  }

  STAGE_U(0, 0, 0);
  STAGE_U(0, 1, 1);
  asm volatile("s_waitcnt vmcnt(4)" ::: "memory");
  __builtin_amdgcn_s_barrier();
  RD(f, 0, 0);

#pragma unroll 1
  for (int it = 0; it < 2; ++it) {
    int k2 = it * 4 + 2, k3 = it * 4 + 3;
    int k4 = it * 4 + 4; k4 = k4 < 8 ? k4 : 7;  // dead dup on last iter
    int k5 = it * 4 + 5; k5 = k5 < 8 ? k5 : 7;
    PHASE(0, 1, g, f, STAGE_U(1, 0, k2));
    PHASE(1, 0, f, g, STAGE_U(1, 1, k3));
    PHASE(1, 1, g, f, STAGE_U(0, 0, k4));
    PHASE(0, 0, f, g, STAGE_U(0, 1, k5));
  }

#undef PHASE
#undef MALL
#undef MROW
#undef RD
#undef STAGE_U

  __syncthreads();  // drain in-flight LDS ops before T reuse

  // ---- fused epilogue: exp, E store, ET store (LDS transpose), Z sums ----
  const int TS = 136;  // padded LDS row stride (u16) for 32x128 slice
  u16* T = ldsA;
  float colacc[4] = {0.f, 0.f, 0.f, 0.f};
#pragma unroll
  for (int s = 0; s < 4; s++) {
    if (wm == (s >> 1)) {
      int smi0 = (s & 1) * 2;
#pragma unroll
      for (int mi2 = 0; mi2 < 2; mi2++) {
        int mi = smi0 + mi2;
        float rowp[4] = {0.f, 0.f, 0.f, 0.f};
#pragma unroll
        for (int ni = 0; ni < 4; ni++) {
          int j = n0 + wn * 64 + ni * 16 + lrow;
          bool jv = j < 1600;
#pragma unroll
          for (int r = 0; r < 4; r++) {
            int i = m0 + wm * 64 + mi * 16 + lquad * 4 + r;
            float e = __expf(acc[mi][ni][r]);
            T[(mi2 * 16 + lquad * 4 + r) * TS + wn * 64 + ni * 16 + lrow] = f2bf(e);
            rowp[r] += jv ? e : 0.f;
            colacc[ni] += (i < 1600) ? e : 0.f;
          }
        }
#pragma unroll
        for (int r = 0; r < 4; r++) {
          float v = rowp[r];
          v += __shfl_xor(v, 1);
          v += __shfl_xor(v, 2);
          v += __shfl_xor(v, 4);
          v += __shfl_xor(v, 8);
          int i = m0 + wm * 64 + mi * 16 + lquad * 4 + r;
          if (lrow == 0 && i < 1600) atomicAdd(&Zrow[b * 1600 + i], v);
        }
      }
    }
    __syncthreads();
    // E rows: 32 rows x 128 cols, 16B coalesced stores
#pragma unroll
    for (int p = 0; p < 2; p++) {
      int jj = tid + p * 256;
      int ml = jj >> 4, n8 = jj & 15;
      int gi = m0 + s * 32 + ml, gj = n0 + n8 * 8;
      if (gi < 1600 && gj < 1600)
        *(uint4*)(Eb + (size_t)gi * 1600 + gj) = *(const uint4*)&T[ml * TS + n8 * 8];
    }
    // ET rows: transposed, 8B stores
#pragma unroll
    for (int p = 0; p < 4; p++) {
      int jj = tid + p * 256;
      int n = jj >> 3, m4 = jj & 7;
      int gm = m0 + s * 32 + m4 * 4, gn = n0 + n;
      if (gn < 1600 && gm < 1600) {
        ushort4 v;
        v.x = T[(m4 * 4 + 0) * TS + n];
        v.y = T[(m4 * 4 + 1) * TS + n];
        v.z = T[(m4 * 4 + 2) * TS + n];
        v.w = T[(m4 * 4 + 3) * TS + n];
        *(ushort4*)(ETb + (size_t)gn * 1600 + gm) = v;
      }
    }
    __syncthreads();
  }
#pragma unroll
  for (int ni = 0; ni < 4; ni++) {
    float v = colacc[ni];
    v += __shfl_xor(v, 16);
    v += __shfl_xor(v, 32);
    int j = n0 + wn * 64 + ni * 16 + lrow;
    if (lquad == 0 && j < 1600) atomicAdd(&Zcol[b * 1600 + j], v);
  }
}

// K3: out[idx] = bf16( x[idx] / Z[b][pixel] )   (both inputs via blockIdx.y)
__global__ void scale_div(const float* __restrict__ ex, const float* __restrict__ qu,
                          const float* __restrict__ Zcol, const float* __restrict__ Zrow,
                          u16* __restrict__ ebf, u16* __restrict__ qbf) {
  const float* x; const float* Z; u16* o;
  if (blockIdx.y == 0) { x = ex; Z = Zcol; o = ebf; }
  else { x = qu; Z = Zrow; o = qbf; }
  size_t idx = (size_t)blockIdx.x * 256 + threadIdx.x;  // 13,107,200
  int b = (int)(idx / 819200);
  int i = (int)(idx % 1600);
  o[idx] = f2bf(x[idx] / Z[b * 1600 + i]);
}

// ---------------------------------------------------------------------------
// K4: att GEMMs. A = proj (512x1600 K-major), B = E/ET rows, C -> padded
// pixel layout bf16. K = 1600 = 50 phases: 12 iters + 2-phase tail.
// (r7-proven: 128^2, 2 blocks/CU, -13us vs 256x224 on this small-K shape.)
// ---------------------------------------------------------------------------
__global__ __launch_bounds__(256, 2) void att_gemm128(
    const u16* __restrict__ Aw1, const u16* __restrict__ Bp1, u16* __restrict__ C1,
    const u16* __restrict__ Aw2, const u16* __restrict__ Bp2, u16* __restrict__ C2) {
  __shared__ u16 ldsA[16384];  // [4 regions][128 rows][32 elems]
  __shared__ u16 ldsB[16384];
  int tid = threadIdx.x;
  int flat = blockIdx.x + blockIdx.y * 13 + blockIdx.z * 52;  // 13x4x32 = 1664
  int wrk = (flat & 7) * 208 + (flat >> 3);                   // chunked XCD swizzle
  int z = wrk / 52;
  int r2 = wrk - z * 52;
  int by = r2 / 13, bx = r2 - by * 13;
  int b = z & 15;
  const u16* Aw = (z < 16 ? Aw1 : Aw2) + (size_t)b * 819200;
  const u16* Bp = (z < 16 ? Bp1 : Bp2) + (size_t)b * 2560000;
  u16* Cb = (z < 16 ? C1 : C2) + (size_t)b * 903168;
  int p0 = bx * 128, c0 = by * 128;

  int rl = tid >> 2;                      // 0..63
  int cs = (tid & 3) ^ ((rl >> 1) & 3);   // swizzled 16B source chunk (of 4)
  const char* pA0 = (const char*)(Aw + (size_t)(c0 + rl) * 1600) + cs * 16;
  const char* pA1 = pA0 + 64 * 3200;
  int pp0 = p0 + rl; pp0 = pp0 < 1600 ? pp0 : 1599;
  const char* pB0 = (const char*)(Bp + (size_t)pp0 * 1600) + cs * 16;
  int pp1 = p0 + 64 + rl; pp1 = pp1 < 1600 ? pp1 : 1599;
  const char* pB1 = (const char*)(Bp + (size_t)pp1 * 1600) + cs * 16;

  char* ldsAb = (char*)ldsA;
  char* ldsBb = (char*)ldsB;
  int dstT = tid * 16;

#define STAGE_U(d, kh, ks)                                              \
  {                                                                     \
    int ko = (ks) * 64;                                                 \
    int ro = ((d) * 2 + (kh)) * 8192;                                   \
    gll16(pA0 + ko, ldsAb + ro + dstT);                                 \
    gll16(pA1 + ko, ldsAb + ro + 4096 + dstT);                          \
    gll16(pB0 + ko, ldsBb + ro + dstT);                                 \
    gll16(pB1 + ko, ldsBb + ro + 4096 + dstT);                          \
  }

  int wid = tid >> 6, lane = tid & 63;
  int wm = wid & 1, wn = wid >> 1;
  int lrow = lane & 15, lquad = lane >> 4;
  int csel = (lquad ^ ((lrow >> 1) & 3)) << 4;
  int aBase = (wm * 64 + lrow) * 64 + csel;
  int bBase = (wn * 64 + lrow) * 64 + csel;

  const f32x4 fzero = {0.f, 0.f, 0.f, 0.f};
  f32x4 acc[4][4];
#pragma unroll
  for (int mi = 0; mi < 4; mi++)
#pragma unroll
    for (int ni = 0; ni < 4; ni++) acc[mi][ni] = fzero;

  bf16x8 fa0, fa1, fa2, fa3, fb0, fb1, fb2, fb3;
  bf16x8 ga0, ga1, ga2, ga3, gb0, gb1, gb2, gb3;

#define RD(pre, d, kh)                                                  \
  {                                                                     \
    const char* ra_ = ldsAb + ((d) * 2 + (kh)) * 8192 + aBase;          \
    const char* rb_ = ldsBb + ((d) * 2 + (kh)) * 8192 + bBase;          \
    pre##a0 = *(const bf16x8*)(ra_);                                    \
    pre##a1 = *(const bf16x8*)(ra_ + 1024);                             \
    pre##a2 = *(const bf16x8*)(ra_ + 2048);                             \
    pre##a3 = *(const bf16x8*)(ra_ + 3072);                             \
    pre##b0 = *(const bf16x8*)(rb_);                                    \
    pre##b1 = *(const bf16x8*)(rb_ + 1024);                             \
    pre##b2 = *(const bf16x8*)(rb_ + 2048);                             \
    pre##b3 = *(const bf16x8*)(rb_ + 3072);                             \
  }

#define MROW(mi, av, pre)                                                               \
  acc[mi][0] = __builtin_amdgcn_mfma_f32_16x16x32_bf16(av, pre##b0, acc[mi][0], 0, 0, 0); \
  acc[mi][1] = __builtin_amdgcn_mfma_f32_16x16x32_bf16(av, pre##b1, acc[mi][1], 0, 0, 0); \
  acc[mi][2] = __builtin_amdgcn_mfma_f32_16x16x32_bf16(av, pre##b2, acc[mi][2], 0, 0, 0); \
  acc[mi][3] = __builtin_amdgcn_mfma_f32_16x16x32_bf16(av, pre##b3, acc[mi][3], 0, 0, 0);

#define MALL(pre)                                                              \
  MROW(0, pre##a0, pre) MROW(1, pre##a1, pre) MROW(2, pre##a2, pre) MROW(3, pre##a3, pre)

#define PHASE(rd_d, rd_kh, rdp, cp, STG)                                       \
  {                                                                            \
    STG;                                                                       \
    asm volatile("s_waitcnt vmcnt(4)" ::: "memory");                           \
    __builtin_amdgcn_s_barrier();                                              \
    RD(rdp, rd_d, rd_kh);                                                      \
    __builtin_amdgcn_s_setprio(1);                                             \
    MALL(cp)                                                                   \
    __builtin_amdgcn_s_setprio(0);                                             \
  }

  STAGE_U(0, 0, 0);
  STAGE_U(0, 1, 1);
  asm volatile("s_waitcnt vmcnt(4)" ::: "memory");  // R0 landed
  __builtin_amdgcn_s_barrier();
  RD(f, 0, 0);

#pragma unroll 1
  for (int it = 0; it < 12; ++it) {
    int k2 = it * 4 + 2, k3 = it * 4 + 3, k4 = it * 4 + 4, k5 = it * 4 + 5;  // <= 49
    PHASE(0, 1, g, f, STAGE_U(1, 0, k2));
    PHASE(1, 0, f, g, STAGE_U(1, 1, k3));
    PHASE(1, 1, g, f, STAGE_U(0, 0, k4));
    PHASE(0, 0, f, g, STAGE_U(0, 1, k5));
  }
  // tail: ks48 in R0 (f holds frags), ks49 in R1
  asm volatile("s_waitcnt vmcnt(0)" ::: "memory");
  __builtin_amdgcn_s_barrier();
  RD(g, 0, 1);
  __builtin_amdgcn_s_setprio(1);
  MALL(f)
  MALL(g)
  __builtin_amdgcn_s_setprio(0);

#undef PHASE
#undef MALL
#undef MROW
#undef RD
#undef STAGE_U

#pragma unroll
  for (int mi = 0; mi < 4; mi++) {
#pragma unroll
    for (int r = 0; r < 4; r++) {
      int o = c0 + wm * 64 + mi * 16 + lquad * 4 + r;
#pragma unroll
      for (int ni = 0; ni < 4; ni++) {
        int p = p0 + wn * 64 + ni * 16 + lrow;
        if (p < 1600) {
          int y = p / 40, x = p - y * 40;
          Cb[(size_t)((y + 1) * 42 + (x + 1)) * 512 + o] = f2bf(acc[mi][ni][r]);
        }
      }
    }
  }
}

// ---------------------------------------------------------------------------
// K5: both 3x3 convs, 256(o)x224(p) tile, single-barrier 4-phase +
// fragment prefetch (r5-proven best: 244us on this large-K shape).
// ---------------------------------------------------------------------------
__global__ __launch_bounds__(512, 2) void conv_gemmpf(
    const u16* __restrict__ W1, const u16* __restrict__ ATT1,
    const u16* __restrict__ W2, const u16* __restrict__ ATT2,
    float* __restrict__ out) {
  __shared__ u16 ldsA[32768];  // [2][2][256 rows][32 elems]
  __shared__ u16 ldsB[32768];  // rows 224+ dummy
  int tid = threadIdx.x;
  int z = blockIdx.z, b = z & 15, sel2 = z >> 4;
  const u16* W = sel2 ? W2 : W1;
  const u16* attb = (sel2 ? ATT2 : ATT1) + (size_t)b * 903168;
  float* outb = out + (size_t)b * 1638400 + (size_t)(sel2 ? 512 : 0) * 1600;
  int p0 = blockIdx.x * 224, o0 = blockIdx.y * 256;

  int rl = tid >> 2;
  int cs = (tid & 3) ^ ((rl >> 1) & 3);
  const char* pA0 = (const char*)(W + (size_t)(o0 + rl) * 4608) + cs * 16;
  const char* pA1 = pA0 + 128 * 9216;
  int pp0 = p0 + rl; pp0 = pp0 < 1600 ? pp0 : 1599;
  int y0 = pp0 / 40, x0 = pp0 - y0 * 40;
  const char* pB0 = (const char*)(attb + (size_t)(y0 * 42 + x0) * 512) + cs * 16;
  int pp1 = p0 + 128 + rl; pp1 = pp1 < 1600 ? pp1 : 1599;
  int y1 = pp1 / 40, x1 = pp1 - y1 * 40;
  const char* pB1 = (const char*)(attb + (size_t)(y1 * 42 + x1) * 512) + cs * 16;

  char* ldsAb = (char*)ldsA;
  char* ldsBb = (char*)ldsB;
  int dstT = tid * 16;

#define STAGE_A(d, kh, kt)                                              \
  {                                                                     \
    int ko = (kt) * 128 + (kh) * 64;                                    \
    gll16(pA0 + ko, ldsAb + ((d) * 2 + (kh)) * 16384 + dstT);           \
    gll16(pA1 + ko, ldsAb + ((d) * 2 + (kh)) * 16384 + 8192 + dstT);    \
  }
#define STAGE_B(d, kh, kt)                                              \
  {                                                                     \
    int tp = (kt) >> 3;                                                 \
    int ty = (tp * 11) >> 5;                                            \
    int tx = tp - ty * 3;                                               \
    int ko = (ty * 42 + tx) * 1024 + ((kt) & 7) * 128 + (kh) * 64;      \
    gll16(pB0 + ko, ldsBb + ((d) * 2 + (kh)) * 16384 + dstT);           \
    gll16(pB1 + ko, ldsBb + ((d) * 2 + (kh)) * 16384 + 8192 + dstT);    \
  }
#define STAGE_U(d, kh, kt) { STAGE_A(d, kh, kt); STAGE_B(d, kh, kt); }

  int wid = tid >> 6, lane = tid & 63;
  int wm = wid & 3, wn = wid >> 2;
  int lrow = lane & 15, lquad = lane >> 4;
  int csel = (lquad ^ ((lrow >> 1) & 3)) << 4;
  int aBase = (wm * 64 + lrow) * 64 + csel;
  int bBase = (wn * 112 + lrow) * 64 + csel;

  const f32x4 fzero = {0.f, 0.f, 0.f, 0.f};
  f32x4 acc[4][7];
#pragma unroll
  for (int mi = 0; mi < 4; mi++)
#pragma unroll
    for (int ni = 0; ni < 7; ni++) acc[mi][ni] = fzero;

  bf16x8 fa0, fa1, fa2, fa3, fb0, fb1, fb2, fb3, fb4, fb5, fb6;
  bf16x8 ga0, ga1, ga2, ga3, gb0, gb1, gb2, gb3, gb4, gb5, gb6;

#define RD(pre, d, kh)                                                  \
  {                                                                     \
    const char* ra_ = ldsAb + ((d) * 2 + (kh)) * 16384 + aBase;         \
    const char* rb_ = ldsBb + ((d) * 2 + (kh)) * 16384 + bBase;         \
    pre##a0 = *(const bf16x8*)(ra_);                                    \
    pre##a1 = *(const bf16x8*)(ra_ + 1024);                             \
    pre##a2 = *(const bf16x8*)(ra_ + 2048);                             \
    pre##a3 = *(const bf16x8*)(ra_ + 3072);                             \
    pre##b0 = *(const bf16x8*)(rb_);                                    \
    pre##b1 = *(const bf16x8*)(rb_ + 1024);                             \
    pre##b2 = *(const bf16x8*)(rb_ + 2048);                             \
    pre##b3 = *(const bf16x8*)(rb_ + 3072);                             \
    pre##b4 = *(const bf16x8*)(rb_ + 4096);                             \
    pre##b5 = *(const bf16x8*)(rb_ + 5120);                             \
    pre##b6 = *(const bf16x8*)(rb_ + 6144);                             \
  }

#define MROW(mi, av, pre)                                                               \
  acc[mi][0] = __builtin_amdgcn_mfma_f32_16x16x32_bf16(av, pre##b0, acc[mi][0], 0, 0, 0); \
  acc[mi][1] = __builtin_amdgcn_mfma_f32_16x16x32_bf16(av, pre##b1, acc[mi][1], 0, 0, 0); \
  acc[mi][2] = __builtin_amdgcn_mfma_f32_16x16x32_bf16(av, pre##b2, acc[mi][2], 0, 0, 0); \
  acc[mi][3] = __builtin_amdgcn_mfma_f32_16x16x32_bf16(av, pre##b3, acc[mi][3], 0, 0, 0); \
  acc[mi][4] = __builtin_amdgcn_mfma_f32_16x16x32_bf16(av, pre##b4, acc[mi][4], 0, 0, 0); \
  acc[mi][5] = __builtin_amdgcn_mfma_f32_16x16x32_bf16(av, pre##b5, acc[mi][5], 0, 0, 0); \
  acc[mi][6] = __builtin_amdgcn_mfma_f32_16x16x32_bf16(av, pre##b6, acc[mi][6], 0, 0, 0);

#define PHASE(rd_d, rd_kh, rdp, cp, STG)                                       \
  {                                                                            \
    STG;                                                                       \
    asm volatile("s_waitcnt vmcnt(4)" ::: "memory");                           \
    __builtin_amdgcn_s_barrier();                                              \
    RD(rdp, rd_d, rd_kh);                                                      \
    __builtin_amdgcn_s_setprio(1);                                             \
    MROW(0, cp##a0, cp)                                                        \
    MROW(1, cp##a1, cp)                                                        \
    MROW(2, cp##a2, cp)                                                        \
    MROW(3, cp##a3, cp)                                                        \
    __builtin_amdgcn_s_setprio(0);                                             \
  }

  STAGE_U(0, 0, 0);
  STAGE_U(0, 1, 0);
  asm volatile("s_waitcnt vmcnt(4)" ::: "memory");
  __builtin_amdgcn_s_barrier();
  RD(f, 0, 0);

#pragma unroll 1
  for (int it = 0; it < 36; ++it) {
    int kt1 = it * 2 + 1;
    int kt2 = it < 35 ? it * 2 + 2 : 71;  // clamped; garbage on last iter, unread
    PHASE(0, 1, g, f, STAGE_U(1, 0, kt1));
    PHASE(1, 0, f, g, STAGE_U(1, 1, kt1));
    PHASE(1, 1, g, f, STAGE_U(0, 0, kt2));
    PHASE(0, 0, f, g, STAGE_U(0, 1, kt2));
  }

#undef PHASE
#undef MROW
#undef RD
#undef STAGE_U
#undef STAGE_A
#undef STAGE_B

#pragma unroll
  for (int mi = 0; mi < 4; mi++) {
#pragma unroll
    for (int r = 0; r < 4; r++) {
      int o = o0 + wm * 64 + mi * 16 + lquad * 4 + r;
      float* orow = outb + (size_t)o * 1600;
#pragma unroll
      for (int ni = 0; ni < 7; ni++) {
        int p = p0 + wn * 112 + ni * 16 + lrow;
        if (p < 1600) orow[p] = acc[mi][ni][r];
      }
    }
  }
}

// ---------------------------------------------------------------------------
extern "C" void kernel_launch(void* const* d_in, const int* in_sizes, int n_in,
                              void* d_out, int out_size, void* d_ws, size_t ws_size,
                              hipStream_t stream) {
  const float* ex = (const float*)d_in[0];
  const float* qu = (const float*)d_in[1];
  const float* w_e = (const float*)d_in[2];
  const float* w_q = (const float*)d_in[3];
  const float* w_c1 = (const float*)d_in[4];
  const float* w_c2 = (const float*)d_in[5];
  float* out = (float*)d_out;
  char* ws = (char*)d_ws;

  u16* E     = (u16*)(ws + 0L);            // 81,920,000
  u16* ET    = (u16*)(ws + 81920000L);     // 81,920,000
  u16* xt_e  = (u16*)(ws + 163840000L);    // 26,214,400 (reused as ebf)
  u16* xt_q  = (u16*)(ws + 190054400L);    // 26,214,400 (reused as qbf)
  u16* ecorr = (u16*)(ws + 216268800L);    // 13,107,200
  u16* qcorr = (u16*)(ws + 229376000L);    // 13,107,200
  u16* att_e = (u16*)(ws + 242483200L);    // 28,901,376
  u16* att_q = (u16*)(ws + 271384576L);    // 28,901,376
  float* Zrow = (float*)(ws + 300285952L); // 102,400
  float* Zcol = (float*)(ws + 300388352L); // 102,400
  u16* w_ebf = (u16*)(ws + 300490752L);    // 262,144
  u16* w_qbf = (u16*)(ws + 300752896L);    // 262,144
  u16* wr1   = (u16*)(ws + 301015040L);    // 4,718,592
  u16* wr2   = (u16*)(ws + 305733632L);    // 4,718,592  (total 310,452,224)

  // prep
  transp_cast_x2<<<dim3(50, 16, 32), 256, 0, stream>>>(ex, qu, xt_e, xt_q);
  cast_w<<<dim3(512), 256, 0, stream>>>(w_e, w_q, w_ebf, w_qbf);
  repack_wc<<<dim3(9216, 2), 256, 0, stream>>>(w_c1, w_c2, wr1, wr2);
  // zero pad rings of att_e/att_q (32 x 164 px x 512 ch) + Zrow/Zcol
  zero_pad<<<dim3(33), 256, 0, stream>>>(att_e, Zrow);

  // K1: corr[b][n][o] = sum_c xt[n,c] * w[o,c]
  corr_gemm128<<<dim3(13, 2, 32), 256, 0, stream>>>(
      xt_e, w_ebf, ecorr, xt_q, w_qbf, qcorr);

  // K2: E/ET/Zrow/Zcol fused
  corr_exp128<<<dim3(13, 13, 16), 256, 0, stream>>>(ecorr, qcorr, E, ET, Zrow, Zcol);

  // K3: scale inputs by softmax denominators
  u16* ebf = xt_e;
  u16* qbf = xt_q;
  scale_div<<<dim3(51200, 2), 256, 0, stream>>>(ex, qu, Zcol, Zrow, ebf, qbf);

  // K4: att_q[p][c] = sum_i E[p,i]*ebf[c,i] ; att_e[p][c] = sum_i ET[p,i]*qbf[c,i]
  att_gemm128<<<dim3(13, 4, 32), 256, 0, stream>>>(ebf, E, att_q, qbf, ET, att_e);

  // K5: both convs, 256(o)x224(p) single-barrier 4-phase + frag prefetch
  conv_gemmpf<<<dim3(8, 2, 32), 512, 0, stream>>>(wr1, att_e, wr2, att_q, out);
}

// Round 10
// 789.405 us; speedup vs baseline: 1.1179x; 1.0084x over previous
//
#include <hip/hip_runtime.h>

typedef unsigned short u16;
typedef __attribute__((ext_vector_type(8))) short bf16x8;
typedef __attribute__((ext_vector_type(4))) float f32x4;

__device__ __forceinline__ u16 f2bf(float f) {
  union { float f; unsigned u; } v; v.f = f;
  unsigned u = v.u;
  u += 0x7fffu + ((u >> 16) & 1u);
  return (u16)(u >> 16);
}

// packed f32x2 -> bf16x2 (RNE), gfx950 HW op (no builtin; inline asm)
__device__ __forceinline__ unsigned pk2(float lo, float hi) {
  unsigned r;
  asm("v_cvt_pk_bf16_f32 %0, %1, %2" : "=v"(r) : "v"(lo), "v"(hi));
  return r;
}

__device__ __forceinline__ void gll16(const void* g, void* l) {
  __builtin_amdgcn_global_load_lds(
      (const __attribute__((address_space(1))) void*)g,
      (__attribute__((address_space(3))) void*)l, 16, 0, 0);
}

// ---------------------------------------------------------------------------
// P1: x[b][c][n] f32 -> xt[b][n][c] bf16   (C=512, N=1600), both inputs
// ---------------------------------------------------------------------------
__global__ __launch_bounds__(256) void transp_cast_x2(const float* __restrict__ ex,
                                                      const float* __restrict__ qu,
                                                      u16* __restrict__ xte,
                                                      u16* __restrict__ xtq) {
  __shared__ float t[32][33];
  int z = blockIdx.z;
  int b = z & 15;
  const float* xb = (z < 16 ? ex : qu) + (size_t)b * 819200;
  u16* xtb = (z < 16 ? xte : xtq) + (size_t)b * 819200;
  int n0 = blockIdx.x * 32, c0 = blockIdx.y * 32;
  int tx = threadIdx.x & 31, ty = threadIdx.x >> 5;
#pragma unroll
  for (int k = 0; k < 4; k++) {
    int c = ty + k * 8;
    t[c][tx] = xb[(size_t)(c0 + c) * 1600 + n0 + tx];
  }
  __syncthreads();
#pragma unroll
  for (int k = 0; k < 4; k++) {
    int n = ty + k * 8;
    xtb[(size_t)(n0 + n) * 512 + c0 + tx] = f2bf(t[tx][n]);
  }
}

// P2: cast w_e / w_q (256x512 each) to bf16
__global__ void cast_w(const float* __restrict__ we, const float* __restrict__ wq,
                       u16* __restrict__ oe, u16* __restrict__ oq) {
  int i = blockIdx.x * 256 + threadIdx.x;
  oe[i] = f2bf(we[i]);
  oq[i] = f2bf(wq[i]);
}

// P3: w[o][c][ky][kx] f32 -> wr[o][t*512+c] bf16 (both conv weights)
__global__ void repack_wc(const float* __restrict__ w1, const float* __restrict__ w2,
                          u16* __restrict__ o1, u16* __restrict__ o2) {
  const float* w = blockIdx.y ? w2 : w1;
  u16* wr = blockIdx.y ? o2 : o1;
  int idx = blockIdx.x * 256 + threadIdx.x;  // 2359296 total
  int o = idx / 4608;
  int r = idx - o * 4608;
  int t = r >> 9;
  int c = r & 511;
  wr[idx] = f2bf(w[o * 4608 + c * 9 + t]);
}

// P4: zero only the pad RING of att buffers + Zrow/Zcol
__global__ void zero_pad(u16* __restrict__ att, float* __restrict__ Z) {
  int q = blockIdx.x;
  uint4 zz; zz.x = 0; zz.y = 0; zz.z = 0; zz.w = 0;
  if (q < 32) {
    uint4* base = (uint4*)(att + (size_t)q * 903168);
    for (int i = threadIdx.x; i < 10496; i += 256) {  // 164 px * 64 uint4
      int t = i >> 6, c = i & 63;
      int y, x;
      if (t < 42) { y = 0; x = t; }
      else if (t < 84) { y = 41; x = t - 42; }
      else if (t < 124) { y = 1 + (t - 84); x = 0; }
      else { y = 1 + (t - 124); x = 41; }
      base[(y * 42 + x) * 64 + c] = zz;
    }
  } else {
    uint4* p = (uint4*)Z;  // Zrow+Zcol contiguous: 204800 B = 12800 uint4
    for (int i = threadIdx.x; i < 12800; i += 256) p[i] = zz;
  }
}

// P5: Z -> 1/Z in place (51200 floats: Zrow then Zcol), after K2
__global__ void inv_z(float* __restrict__ Z) {
  int i = blockIdx.x * 256 + threadIdx.x;
  Z[i] = 1.0f / Z[i];
}

// ===========================================================================
// Small-K GEMM template (K1, K2, K4): 128x128 tile, 256 thr (4 waves 2x2),
// 64KB LDS -> 2 blocks/CU; 4-region rotation (region = BK=32 slice), frag
// prefetch, single barrier + counted vmcnt per phase.
// ===========================================================================

// ---------------------------------------------------------------------------
// K1: corr[n][o] = sum_c xt[n,c]*w[o,c].  M=1600, N=256, K=512 (16 phases).
// ---------------------------------------------------------------------------
__global__ __launch_bounds__(256, 2) void corr_gemm128(
    const u16* __restrict__ X1, const u16* __restrict__ Wg1, u16* __restrict__ C1,
    const u16* __restrict__ X2, const u16* __restrict__ Wg2, u16* __restrict__ C2) {
  __shared__ u16 ldsA[16384];
  __shared__ u16 ldsB[16384];
  int tid = threadIdx.x;
  int flat = blockIdx.x + blockIdx.y * 13 + blockIdx.z * 26;  // 832 blocks
  int wrk = (flat & 7) * 104 + (flat >> 3);                   // 832 = 8*104, bijective
  int z = wrk / 26;
  int r2 = wrk - z * 26;
  int by = r2 / 13, bx = r2 - by * 13;
  int b = z & 15;
  const u16* A = (z < 16 ? X1 : X2) + (size_t)b * 819200;
  const u16* B = (z < 16 ? Wg1 : Wg2);
  u16* Cb = (z < 16 ? C1 : C2) + (size_t)b * 409600;
  int m0 = bx * 128, n0 = by * 128;

  int rl = tid >> 2;
  int cs = (tid & 3) ^ ((rl >> 1) & 3);
  int ra0 = m0 + rl; ra0 = ra0 < 1600 ? ra0 : 1599;
  int ra1 = m0 + 64 + rl; ra1 = ra1 < 1600 ? ra1 : 1599;
  const char* pA0 = (const char*)(A + (size_t)ra0 * 512) + cs * 16;
  const char* pA1 = (const char*)(A + (size_t)ra1 * 512) + cs * 16;
  const char* pB0 = (const char*)(B + (size_t)(n0 + rl) * 512) + cs * 16;
  const char* pB1 = (const char*)(B + (size_t)(n0 + 64 + rl) * 512) + cs * 16;

  char* ldsAb = (char*)ldsA;
  char* ldsBb = (char*)ldsB;
  int dstT = tid * 16;

#define STAGE_U(d, kh, ks)                                              \
  {                                                                     \
    int ko = (ks) * 64;                                                 \
    int ro = ((d) * 2 + (kh)) * 8192;                                   \
    gll16(pA0 + ko, ldsAb + ro + dstT);                                 \
    gll16(pA1 + ko, ldsAb + ro + 4096 + dstT);                          \
    gll16(pB0 + ko, ldsBb + ro + dstT);                                 \
    gll16(pB1 + ko, ldsBb + ro + 4096 + dstT);                          \
  }

  int wid = tid >> 6, lane = tid & 63;
  int wm = wid & 1, wn = wid >> 1;
  int lrow = lane & 15, lquad = lane >> 4;
  int csel = (lquad ^ ((lrow >> 1) & 3)) << 4;
  int aBase = (wm * 64 + lrow) * 64 + csel;
  int bBase = (wn * 64 + lrow) * 64 + csel;

  const f32x4 fzero = {0.f, 0.f, 0.f, 0.f};
  f32x4 acc[4][4];
#pragma unroll
  for (int mi = 0; mi < 4; mi++)
#pragma unroll
    for (int ni = 0; ni < 4; ni++) acc[mi][ni] = fzero;

  bf16x8 fa0, fa1, fa2, fa3, fb0, fb1, fb2, fb3;
  bf16x8 ga0, ga1, ga2, ga3, gb0, gb1, gb2, gb3;

#define RD(pre, d, kh)                                                  \
  {                                                                     \
    const char* ra_ = ldsAb + ((d) * 2 + (kh)) * 8192 + aBase;          \
    const char* rb_ = ldsBb + ((d) * 2 + (kh)) * 8192 + bBase;          \
    pre##a0 = *(const bf16x8*)(ra_);                                    \
    pre##a1 = *(const bf16x8*)(ra_ + 1024);                             \
    pre##a2 = *(const bf16x8*)(ra_ + 2048);                             \
    pre##a3 = *(const bf16x8*)(ra_ + 3072);                             \
    pre##b0 = *(const bf16x8*)(rb_);                                    \
    pre##b1 = *(const bf16x8*)(rb_ + 1024);                             \
    pre##b2 = *(const bf16x8*)(rb_ + 2048);                             \
    pre##b3 = *(const bf16x8*)(rb_ + 3072);                             \
  }

#define MROW(mi, av, pre)                                                               \
  acc[mi][0] = __builtin_amdgcn_mfma_f32_16x16x32_bf16(av, pre##b0, acc[mi][0], 0, 0, 0); \
  acc[mi][1] = __builtin_amdgcn_mfma_f32_16x16x32_bf16(av, pre##b1, acc[mi][1], 0, 0, 0); \
  acc[mi][2] = __builtin_amdgcn_mfma_f32_16x16x32_bf16(av, pre##b2, acc[mi][2], 0, 0, 0); \
  acc[mi][3] = __builtin_amdgcn_mfma_f32_16x16x32_bf16(av, pre##b3, acc[mi][3], 0, 0, 0);

#define MALL(pre)                                                              \
  MROW(0, pre##a0, pre) MROW(1, pre##a1, pre) MROW(2, pre##a2, pre) MROW(3, pre##a3, pre)

#define PHASE(rd_d, rd_kh, rdp, cp, STG)                                       \
  {                                                                            \
    STG;                                                                       \
    asm volatile("s_waitcnt vmcnt(4)" ::: "memory");                           \
    __builtin_amdgcn_s_barrier();                                              \
    RD(rdp, rd_d, rd_kh);                                                      \
    __builtin_amdgcn_s_setprio(1);                                             \
    MALL(cp)                                                                   \
    __builtin_amdgcn_s_setprio(0);                                             \
  }

  STAGE_U(0, 0, 0);
  STAGE_U(0, 1, 1);
  asm volatile("s_waitcnt vmcnt(4)" ::: "memory");
  __builtin_amdgcn_s_barrier();
  RD(f, 0, 0);

#pragma unroll 1
  for (int it = 0; it < 4; ++it) {
    int k2 = it * 4 + 2, k3 = it * 4 + 3;
    int k4 = it * 4 + 4; k4 = k4 < 16 ? k4 : 15;  // dead dup on last iter
    int k5 = it * 4 + 5; k5 = k5 < 16 ? k5 : 15;
    PHASE(0, 1, g, f, STAGE_U(1, 0, k2));
    PHASE(1, 0, f, g, STAGE_U(1, 1, k3));
    PHASE(1, 1, g, f, STAGE_U(0, 0, k4));
    PHASE(0, 0, f, g, STAGE_U(0, 1, k5));
  }

#undef PHASE
#undef MALL
#undef MROW
#undef RD
#undef STAGE_U

#pragma unroll
  for (int mi = 0; mi < 4; mi++) {
#pragma unroll
    for (int r = 0; r < 4; r++) {
      int i = m0 + wm * 64 + mi * 16 + lquad * 4 + r;
      if (i >= 1600) continue;
#pragma unroll
      for (int ni = 0; ni < 4; ni++) {
        int j = n0 + wn * 64 + ni * 16 + lrow;
        Cb[(size_t)i * 256 + j] = f2bf(acc[mi][ni][r]);
      }
    }
  }
}

// ---------------------------------------------------------------------------
// K2: E = exp(ecorr * qcorr^T)  [1600x1600 per batch, K=256 -> 8 phases].
// ---------------------------------------------------------------------------
__global__ __launch_bounds__(256, 2) void corr_exp128(
    const u16* __restrict__ A, const u16* __restrict__ B, u16* __restrict__ E,
    u16* __restrict__ ET, float* __restrict__ Zrow, float* __restrict__ Zcol) {
  __shared__ u16 ldsA[16384];
  __shared__ u16 ldsB[16384];
  int tid = threadIdx.x;
  int flat = blockIdx.x + blockIdx.y * 13 + blockIdx.z * 169;  // 2704 blocks
  int wrk = (flat & 7) * 338 + (flat >> 3);                    // 2704 = 8*338
  int b = wrk / 169;
  int r2 = wrk - b * 169;
  int by = r2 / 13, bx = r2 - by * 13;
  const u16* Ab = A + (size_t)b * 409600;
  const u16* Bb = B + (size_t)b * 409600;
  u16* Eb = E + (size_t)b * 2560000;
  u16* ETb = ET + (size_t)b * 2560000;
  int m0 = bx * 128, n0 = by * 128;

  int rl = tid >> 2;
  int cs = (tid & 3) ^ ((rl >> 1) & 3);
  int ra0 = m0 + rl; ra0 = ra0 < 1600 ? ra0 : 1599;
  int ra1 = m0 + 64 + rl; ra1 = ra1 < 1600 ? ra1 : 1599;
  int rb0 = n0 + rl; rb0 = rb0 < 1600 ? rb0 : 1599;
  int rb1 = n0 + 64 + rl; rb1 = rb1 < 1600 ? rb1 : 1599;
  const char* pA0 = (const char*)(Ab + (size_t)ra0 * 256) + cs * 16;
  const char* pA1 = (const char*)(Ab + (size_t)ra1 * 256) + cs * 16;
  const char* pB0 = (const char*)(Bb + (size_t)rb0 * 256) + cs * 16;
  const char* pB1 = (const char*)(Bb + (size_t)rb1 * 256) + cs * 16;

  char* ldsAb = (char*)ldsA;
  char* ldsBb = (char*)ldsB;
  int dstT = tid * 16;

#define STAGE_U(d, kh, ks)                                              \
  {                                                                     \
    int ko = (ks) * 64;                                                 \
    int ro = ((d) * 2 + (kh)) * 8192;                                   \
    gll16(pA0 + ko, ldsAb + ro + dstT);                                 \
    gll16(pA1 + ko, ldsAb + ro + 4096 + dstT);                          \
    gll16(pB0 + ko, ldsBb + ro + dstT);                                 \
    gll16(pB1 + ko, ldsBb + ro + 4096 + dstT);                          \
  }

  int wid = tid >> 6, lane = tid & 63;
  int wm = wid & 1, wn = wid >> 1;
  int lrow = lane & 15, lquad = lane >> 4;
  int csel = (lquad ^ ((lrow >> 1) & 3)) << 4;
  int aBase = (wm * 64 + lrow) * 64 + csel;
  int bBase = (wn * 64 + lrow) * 64 + csel;

  const f32x4 fzero = {0.f, 0.f, 0.f, 0.f};
  f32x4 acc[4][4];
#pragma unroll
  for (int mi = 0; mi < 4; mi++)
#pragma unroll
    for (int ni = 0; ni < 4; ni++) acc[mi][ni] = fzero;

  bf16x8 fa0, fa1, fa2, fa3, fb0, fb1, fb2, fb3;
  bf16x8 ga0, ga1, ga2, ga3, gb0, gb1, gb2, gb3;

#define RD(pre, d, kh)                                                  \
  {                                                                     \
    const char* ra_ = ldsAb + ((d) * 2 + (kh)) * 8192 + aBase;          \
    const char* rb_ = ldsBb + ((d) * 2 + (kh)) * 8192 + bBase;          \
    pre##a0 = *(const bf16x8*)(ra_);                                    \
    pre##a1 = *(const bf16x8*)(ra_ + 1024);                             \
    pre##a2 = *(const bf16x8*)(ra_ + 2048);                             \
    pre##a3 = *(const bf16x8*)(ra_ + 3072);                             \
    pre##b0 = *(const bf16x8*)(rb_);                                    \
    pre##b1 = *(const bf16x8*)(rb_ + 1024);                             \
    pre##b2 = *(const bf16x8*)(rb_ + 2048);                             \
    pre##b3 = *(const bf16x8*)(rb_ + 3072);                             \
  }

#define MROW(mi, av, pre)                                                               \
  acc[mi][0] = __builtin_amdgcn_mfma_f32_16x16x32_bf16(av, pre##b0, acc[mi][0], 0, 0, 0); \
  acc[mi][1] = __builtin_amdgcn_mfma_f32_16x16x32_bf16(av, pre##b1, acc[mi][1], 0, 0, 0); \
  acc[mi][2] = __builtin_amdgcn_mfma_f32_16x16x32_bf16(av, pre##b2, acc[mi][2], 0, 0, 0); \
  acc[mi][3] = __builtin_amdgcn_mfma_f32_16x16x32_bf16(av, pre##b3, acc[mi][3], 0, 0, 0);

#define MALL(pre)                                                              \
  MROW(0, pre##a0, pre) MROW(1, pre##a1, pre) MROW(2, pre##a2, pre) MROW(3, pre##a3, pre)

#define PHASE(rd_d, rd_kh, rdp, cp, STG)                                       \
  {                                                                            \
    STG;                                                                       \
    asm volatile("s_waitcnt vmcnt(4)" ::: "memory");                           \
    __builtin_amdgcn_s_barrier();                                              \
    RD(rdp, rd_d, rd_kh);                                                      \
    __builtin_amdgcn_s_setprio(1);                                             \
    MALL(cp)                                                                   \
    __builtin_amdgcn_s_setprio(0);                                             \
  }

  STAGE_U(0, 0, 0);
  STAGE_U(0, 1, 1);
  asm volatile("s_waitcnt vmcnt(4)" ::: "memory");
  __builtin_amdgcn_s_barrier();
  RD(f, 0, 0);

#pragma unroll 1
  for (int it = 0; it < 2; ++it) {
    int k2 = it * 4 + 2, k3 = it * 4 + 3;
    int k4 = it * 4 + 4; k4 = k4 < 8 ? k4 : 7;  // dead dup on last iter
    int k5 = it * 4 + 5; k5 = k5 < 8 ? k5 : 7;
    PHASE(0, 1, g, f, STAGE_U(1, 0, k2));
    PHASE(1, 0, f, g, STAGE_U(1, 1, k3));
    PHASE(1, 1, g, f, STAGE_U(0, 0, k4));
    PHASE(0, 0, f, g, STAGE_U(0, 1, k5));
  }

#undef PHASE
#undef MALL
#undef MROW
#undef RD
#undef STAGE_U

  __syncthreads();  // drain in-flight LDS ops before T reuse

  // ---- fused epilogue: exp, E store, ET store (LDS transpose), Z sums ----
  const int TS = 136;  // padded LDS row stride (u16) for 32x128 slice
  u16* T = ldsA;
  float colacc[4] = {0.f, 0.f, 0.f, 0.f};
#pragma unroll
  for (int s = 0; s < 4; s++) {
    if (wm == (s >> 1)) {
      int smi0 = (s & 1) * 2;
#pragma unroll
      for (int mi2 = 0; mi2 < 2; mi2++) {
        int mi = smi0 + mi2;
        float rowp[4] = {0.f, 0.f, 0.f, 0.f};
#pragma unroll
        for (int ni = 0; ni < 4; ni++) {
          int j = n0 + wn * 64 + ni * 16 + lrow;
          bool jv = j < 1600;
#pragma unroll
          for (int r = 0; r < 4; r++) {
            int i = m0 + wm * 64 + mi * 16 + lquad * 4 + r;
            float e = __expf(acc[mi][ni][r]);
            T[(mi2 * 16 + lquad * 4 + r) * TS + wn * 64 + ni * 16 + lrow] = f2bf(e);
            rowp[r] += jv ? e : 0.f;
            colacc[ni] += (i < 1600) ? e : 0.f;
          }
        }
#pragma unroll
        for (int r = 0; r < 4; r++) {
          float v = rowp[r];
          v += __shfl_xor(v, 1);
          v += __shfl_xor(v, 2);
          v += __shfl_xor(v, 4);
          v += __shfl_xor(v, 8);
          int i = m0 + wm * 64 + mi * 16 + lquad * 4 + r;
          if (lrow == 0 && i < 1600) atomicAdd(&Zrow[b * 1600 + i], v);
        }
      }
    }
    __syncthreads();
    // E rows: 32 rows x 128 cols, 16B coalesced stores
#pragma unroll
    for (int p = 0; p < 2; p++) {
      int jj = tid + p * 256;
      int ml = jj >> 4, n8 = jj & 15;
      int gi = m0 + s * 32 + ml, gj = n0 + n8 * 8;
      if (gi < 1600 && gj < 1600)
        *(uint4*)(Eb + (size_t)gi * 1600 + gj) = *(const uint4*)&T[ml * TS + n8 * 8];
    }
    // ET rows: transposed, 8B stores
#pragma unroll
    for (int p = 0; p < 4; p++) {
      int jj = tid + p * 256;
      int n = jj >> 3, m4 = jj & 7;
      int gm = m0 + s * 32 + m4 * 4, gn = n0 + n;
      if (gn < 1600 && gm < 1600) {
        ushort4 v;
        v.x = T[(m4 * 4 + 0) * TS + n];
        v.y = T[(m4 * 4 + 1) * TS + n];
        v.z = T[(m4 * 4 + 2) * TS + n];
        v.w = T[(m4 * 4 + 3) * TS + n];
        *(ushort4*)(ETb + (size_t)gn * 1600 + gm) = v;
      }
    }
    __syncthreads();
  }
#pragma unroll
  for (int ni = 0; ni < 4; ni++) {
    float v = colacc[ni];
    v += __shfl_xor(v, 16);
    v += __shfl_xor(v, 32);
    int j = n0 + wn * 64 + ni * 16 + lrow;
    if (lquad == 0 && j < 1600) atomicAdd(&Zcol[b * 1600 + j], v);
  }
}

// ---------------------------------------------------------------------------
// K4 (fused with old K3): att GEMMs with on-the-fly A = x * (1/Z) -> bf16.
// A reg-staged from raw f32 (ds_write into the same swizzled slots), B via
// gll16. Per phase: [6 A/Z loads; 2 B gll16; vmcnt(8) (drains B@P-1);
// barrier; RD; MFMA; A-drain+scale+ds_write; lgkmcnt(0)]. K=1600: 50 phases.
// ---------------------------------------------------------------------------
__global__ __launch_bounds__(256, 2) void att_fuse128(
    const float* __restrict__ Xe, const float* __restrict__ Xq,
    const float* __restrict__ iZc, const float* __restrict__ iZr,
    const u16* __restrict__ E, const u16* __restrict__ ET,
    u16* __restrict__ Cq, u16* __restrict__ Ce) {
  __shared__ u16 ldsA[16384];  // [4 regions][128 rows][32 elems]
  __shared__ u16 ldsB[16384];
  int tid = threadIdx.x;
  int flat = blockIdx.x + blockIdx.y * 13 + blockIdx.z * 52;  // 1664 blocks
  int wrk = (flat & 7) * 208 + (flat >> 3);                   // 1664 = 8*208
  int z = wrk / 52;
  int r2 = wrk - z * 52;
  int by = r2 / 13, bx = r2 - by * 13;
  int b = z & 15;
  const float* X = (z < 16 ? Xe : Xq) + (size_t)b * 819200;
  const float* iZ = (z < 16 ? iZc : iZr) + b * 1600;
  const u16* Bp = (z < 16 ? E : ET) + (size_t)b * 2560000;
  u16* Cb = (z < 16 ? Cq : Ce) + (size_t)b * 903168;
  int p0 = bx * 128, c0 = by * 128;

  int rl = tid >> 2;                      // 0..63
  int cs = (tid & 3) ^ ((rl >> 1) & 3);   // swizzled 8-elem source chunk (of 4)
  const float* pX0 = X + (size_t)(c0 + rl) * 1600 + cs * 8;
  const float* pX1 = pX0 + (size_t)64 * 1600;
  const float* pZ = iZ + cs * 8;
  int pp0 = p0 + rl; pp0 = pp0 < 1600 ? pp0 : 1599;
  const char* pB0 = (const char*)(Bp + (size_t)pp0 * 1600) + cs * 16;
  int pp1 = p0 + 64 + rl; pp1 = pp1 < 1600 ? pp1 : 1599;
  const char* pB1 = (const char*)(Bp + (size_t)pp1 * 1600) + cs * 16;

  char* ldsAb = (char*)ldsA;
  char* ldsBb = (char*)ldsB;
  int dstT = tid * 16;

  float4 a00, a01, a10, a11, zz0, zz1;

#define ALD(ks)                                                         \
  a00 = *(const float4*)(pX0 + (ks) * 32);                              \
  a01 = *(const float4*)(pX0 + (ks) * 32 + 4);                          \
  a10 = *(const float4*)(pX1 + (ks) * 32);                              \
  a11 = *(const float4*)(pX1 + (ks) * 32 + 4);                          \
  zz0 = *(const float4*)(pZ + (ks) * 32);                               \
  zz1 = *(const float4*)(pZ + (ks) * 32 + 4);

#define BST(d, kh, ks)                                                  \
  {                                                                     \
    int ko = (ks) * 64;                                                 \
    int ro = ((d) * 2 + (kh)) * 8192;                                   \
    gll16(pB0 + ko, ldsBb + ro + dstT);                                 \
    gll16(pB1 + ko, ldsBb + ro + 4096 + dstT);                          \
  }

#define AWR(d, kh)                                                      \
  {                                                                     \
    int ro = ((d) * 2 + (kh)) * 8192;                                   \
    uint4 w0, w1;                                                       \
    w0.x = pk2(a00.x * zz0.x, a00.y * zz0.y);                           \
    w0.y = pk2(a00.z * zz0.z, a00.w * zz0.w);                           \
    w0.z = pk2(a01.x * zz1.x, a01.y * zz1.y);                           \
    w0.w = pk2(a01.z * zz1.z, a01.w * zz1.w);                           \
    w1.x = pk2(a10.x * zz0.x, a10.y * zz0.y);                           \
    w1.y = pk2(a10.z * zz0.z, a10.w * zz0.w);                           \
    w1.z = pk2(a11.x * zz1.x, a11.y * zz1.y);                           \
    w1.w = pk2(a11.z * zz1.z, a11.w * zz1.w);                           \
    *(uint4*)(ldsAb + ro + dstT) = w0;                                  \
    *(uint4*)(ldsAb + ro + 4096 + dstT) = w1;                           \
  }

  int wid = tid >> 6, lane = tid & 63;
  int wm = wid & 1, wn = wid >> 1;
  int lrow = lane & 15, lquad = lane >> 4;
  int csel = (lquad ^ ((lrow >> 1) & 3)) << 4;
  int aBase = (wm * 64 + lrow) * 64 + csel;
  int bBase = (wn * 64 + lrow) * 64 + csel;

  const f32x4 fzero = {0.f, 0.f, 0.f, 0.f};
  f32x4 acc[4][4];
#pragma unroll
  for (int mi = 0; mi < 4; mi++)
#pragma unroll
    for (int ni = 0; ni < 4; ni++) acc[mi][ni] = fzero;

  bf16x8 fa0, fa1, fa2, fa3, fb0, fb1, fb2, fb3;
  bf16x8 ga0, ga1, ga2, ga3, gb0, gb1, gb2, gb3;

#define RD(pre, d, kh)                                                  \
  {                                                                     \
    const char* ra_ = ldsAb + ((d) * 2 + (kh)) * 8192 + aBase;          \
    const char* rb_ = ldsBb + ((d) * 2 + (kh)) * 8192 + bBase;          \
    pre##a0 = *(const bf16x8*)(ra_);                                    \
    pre##a1 = *(const bf16x8*)(ra_ + 1024);                             \
    pre##a2 = *(const bf16x8*)(ra_ + 2048);                             \
    pre##a3 = *(const bf16x8*)(ra_ + 3072);                             \
    pre##b0 = *(const bf16x8*)(rb_);                                    \
    pre##b1 = *(const bf16x8*)(rb_ + 1024);                             \
    pre##b2 = *(const bf16x8*)(rb_ + 2048);                             \
    pre##b3 = *(const bf16x8*)(rb_ + 3072);                             \
  }

#define MROW(mi, av, pre)                                                               \
  acc[mi][0] = __builtin_amdgcn_mfma_f32_16x16x32_bf16(av, pre##b0, acc[mi][0], 0, 0, 0); \
  acc[mi][1] = __builtin_amdgcn_mfma_f32_16x16x32_bf16(av, pre##b1, acc[mi][1], 0, 0, 0); \
  acc[mi][2] = __builtin_amdgcn_mfma_f32_16x16x32_bf16(av, pre##b2, acc[mi][2], 0, 0, 0); \
  acc[mi][3] = __builtin_amdgcn_mfma_f32_16x16x32_bf16(av, pre##b3, acc[mi][3], 0, 0, 0);

#define MALL(pre)                                                              \
  MROW(0, pre##a0, pre) MROW(1, pre##a1, pre) MROW(2, pre##a2, pre) MROW(3, pre##a3, pre)

#define PHASE(rd_d, rd_kh, rdp, cp, st_d, st_kh, st_ks)                        \
  {                                                                            \
    ALD(st_ks);                                                                \
    BST(st_d, st_kh, st_ks);                                                   \
    asm volatile("s_waitcnt vmcnt(8)" ::: "memory");                           \
    __builtin_amdgcn_s_barrier();                                              \
    RD(rdp, rd_d, rd_kh);                                                      \
    __builtin_amdgcn_s_setprio(1);                                             \
    MALL(cp)                                                                   \
    __builtin_amdgcn_s_setprio(0);                                             \
    AWR(st_d, st_kh);                                                          \
    asm volatile("s_waitcnt lgkmcnt(0)" ::: "memory");                         \
  }

  // ---- prologue: R0<-ks0, R1<-ks1 (A reg-staged, B gll16); F <- R0 ----
  ALD(0); BST(0, 0, 0); AWR(0, 0);
  ALD(1); BST(0, 1, 1); AWR(0, 1);
  asm volatile("s_waitcnt vmcnt(0)" ::: "memory");
  asm volatile("s_waitcnt lgkmcnt(0)" ::: "memory");
  __builtin_amdgcn_s_barrier();
  RD(f, 0, 0);

#pragma unroll 1
  for (int it = 0; it < 12; ++it) {
    int k2 = it * 4 + 2, k3 = it * 4 + 3, k4 = it * 4 + 4, k5 = it * 4 + 5;  // <= 49
    PHASE(0, 1, g, f, 1, 0, k2);
    PHASE(1, 0, f, g, 1, 1, k3);
    PHASE(1, 1, g, f, 0, 0, k4);
    PHASE(0, 0, f, g, 0, 1, k5);
  }
  // tail: ks48 in R0 (f holds frags), ks49 in R1
  asm volatile("s_waitcnt vmcnt(0)" ::: "memory");
  __builtin_amdgcn_s_barrier();
  RD(g, 0, 1);
  __builtin_amdgcn_s_setprio(1);
  MALL(f)
  MALL(g)
  __builtin_amdgcn_s_setprio(0);

#undef PHASE
#undef MALL
#undef MROW
#undef RD
#undef AWR
#undef BST
#undef ALD

#pragma unroll
  for (int mi = 0; mi < 4; mi++) {
#pragma unroll
    for (int r = 0; r < 4; r++) {
      int o = c0 + wm * 64 + mi * 16 + lquad * 4 + r;
#pragma unroll
      for (int ni = 0; ni < 4; ni++) {
        int p = p0 + wn * 64 + ni * 16 + lrow;
        if (p < 1600) {
          int y = p / 40, x = p - y * 40;
          Cb[(size_t)((y + 1) * 42 + (x + 1)) * 512 + o] = f2bf(acc[mi][ni][r]);
        }
      }
    }
  }
}

// ---------------------------------------------------------------------------
// K5: both 3x3 convs, 256(o)x224(p) tile, single-barrier 4-phase + frag
// prefetch. XCD swizzle: 512 blocks = 8 chunks x 64 (BIJECTIVE — r9 bug was
// *56); each chunk = 4 batches x 8 p-tiles x both o-tiles (B-panel sharing).
// ---------------------------------------------------------------------------
__global__ __launch_bounds__(512, 2) void conv_gemmpf(
    const u16* __restrict__ W1, const u16* __restrict__ ATT1,
    const u16* __restrict__ W2, const u16* __restrict__ ATT2,
    float* __restrict__ out) {
  __shared__ u16 ldsA[32768];  // [2][2][256 rows][32 elems]
  __shared__ u16 ldsB[32768];  // rows 224+ dummy
  int tid = threadIdx.x;
  int h = blockIdx.x + blockIdx.y * 8 + blockIdx.z * 16;  // 512 blocks
  int wrk = (h & 7) * 64 + (h >> 3);                      // 512 = 8*64, bijective
  int by = wrk & 1;
  int q = wrk >> 1;
  int bx = q & 7, z = q >> 3;
  int b = z & 15, sel2 = z >> 4;
  const u16* W = sel2 ? W2 : W1;
  const u16* attb = (sel2 ? ATT2 : ATT1) + (size_t)b * 903168;
  float* outb = out + (size_t)b * 1638400 + (size_t)(sel2 ? 512 : 0) * 1600;
  int p0 = bx * 224, o0 = by * 256;

  int rl = tid >> 2;
  int cs = (tid & 3) ^ ((rl >> 1) & 3);
  const char* pA0 = (const char*)(W + (size_t)(o0 + rl) * 4608) + cs * 16;
  const char* pA1 = pA0 + 128 * 9216;
  int pp0 = p0 + rl; pp0 = pp0 < 1600 ? pp0 : 1599;
  int y0 = pp0 / 40, x0 = pp0 - y0 * 40;
  const char* pB0 = (const char*)(attb + (size_t)(y0 * 42 + x0) * 512) + cs * 16;
  int pp1 = p0 + 128 + rl; pp1 = pp1 < 1600 ? pp1 : 1599;
  int y1 = pp1 / 40, x1 = pp1 - y1 * 40;
  const char* pB1 = (const char*)(attb + (size_t)(y1 * 42 + x1) * 512) + cs * 16;

  char* ldsAb = (char*)ldsA;
  char* ldsBb = (char*)ldsB;
  int dstT = tid * 16;

#define STAGE_A(d, kh, kt)                                              \
  {                                                                     \
    int ko = (kt) * 128 + (kh) * 64;                                    \
    gll16(pA0 + ko, ldsAb + ((d) * 2 + (kh)) * 16384 + dstT);           \
    gll16(pA1 + ko, ldsAb + ((d) * 2 + (kh)) * 16384 + 8192 + dstT);    \
  }
#define STAGE_B(d, kh, kt)                                              \
  {                                                                     \
    int tp = (kt) >> 3;                                                 \
    int ty = (tp * 11) >> 5;                                            \
    int tx = tp - ty * 3;                                               \
    int ko = (ty * 42 + tx) * 1024 + ((kt) & 7) * 128 + (kh) * 64;      \
    gll16(pB0 + ko, ldsBb + ((d) * 2 + (kh)) * 16384 + dstT);           \
    gll16(pB1 + ko, ldsBb + ((d) * 2 + (kh)) * 16384 + 8192 + dstT);    \
  }
#define STAGE_U(d, kh, kt) { STAGE_A(d, kh, kt); STAGE_B(d, kh, kt); }

  int wid = tid >> 6, lane = tid & 63;
  int wm = wid & 3, wn = wid >> 2;
  int lrow = lane & 15, lquad = lane >> 4;
  int csel = (lquad ^ ((lrow >> 1) & 3)) << 4;
  int aBase = (wm * 64 + lrow) * 64 + csel;
  int bBase = (wn * 112 + lrow) * 64 + csel;

  const f32x4 fzero = {0.f, 0.f, 0.f, 0.f};
  f32x4 acc[4][7];
#pragma unroll
  for (int mi = 0; mi < 4; mi++)
#pragma unroll
    for (int ni = 0; ni < 7; ni++) acc[mi][ni] = fzero;

  bf16x8 fa0, fa1, fa2, fa3, fb0, fb1, fb2, fb3, fb4, fb5, fb6;
  bf16x8 ga0, ga1, ga2, ga3, gb0, gb1, gb2, gb3, gb4, gb5, gb6;

#define RD(pre, d, kh)                                                  \
  {                                                                     \
    const char* ra_ = ldsAb + ((d) * 2 + (kh)) * 16384 + aBase;         \
    const char* rb_ = ldsBb + ((d) * 2 + (kh)) * 16384 + bBase;         \
    pre##a0 = *(const bf16x8*)(ra_);                                    \
    pre##a1 = *(const bf16x8*)(ra_ + 1024);                             \
    pre##a2 = *(const bf16x8*)(ra_ + 2048);                             \
    pre##a3 = *(const bf16x8*)(ra_ + 3072);                             \
    pre##b0 = *(const bf16x8*)(rb_);                                    \
    pre##b1 = *(const bf16x8*)(rb_ + 1024);                             \
    pre##b2 = *(const bf16x8*)(rb_ + 2048);                             \
    pre##b3 = *(const bf16x8*)(rb_ + 3072);                             \
    pre##b4 = *(const bf16x8*)(rb_ + 4096);                             \
    pre##b5 = *(const bf16x8*)(rb_ + 5120);                             \
    pre##b6 = *(const bf16x8*)(rb_ + 6144);                             \
  }

#define MROW(mi, av, pre)                                                               \
  acc[mi][0] = __builtin_amdgcn_mfma_f32_16x16x32_bf16(av, pre##b0, acc[mi][0], 0, 0, 0); \
  acc[mi][1] = __builtin_amdgcn_mfma_f32_16x16x32_bf16(av, pre##b1, acc[mi][1], 0, 0, 0); \
  acc[mi][2] = __builtin_amdgcn_mfma_f32_16x16x32_bf16(av, pre##b2, acc[mi][2], 0, 0, 0); \
  acc[mi][3] = __builtin_amdgcn_mfma_f32_16x16x32_bf16(av, pre##b3, acc[mi][3], 0, 0, 0); \
  acc[mi][4] = __builtin_amdgcn_mfma_f32_16x16x32_bf16(av, pre##b4, acc[mi][4], 0, 0, 0); \
  acc[mi][5] = __builtin_amdgcn_mfma_f32_16x16x32_bf16(av, pre##b5, acc[mi][5], 0, 0, 0); \
  acc[mi][6] = __builtin_amdgcn_mfma_f32_16x16x32_bf16(av, pre##b6, acc[mi][6], 0, 0, 0);

#define PHASE(rd_d, rd_kh, rdp, cp, STG)                                       \
  {                                                                            \
    STG;                                                                       \
    asm volatile("s_waitcnt vmcnt(4)" ::: "memory");                           \
    __builtin_amdgcn_s_barrier();                                              \
    RD(rdp, rd_d, rd_kh);                                                      \
    __builtin_amdgcn_s_setprio(1);                                             \
    MROW(0, cp##a0, cp)                                                        \
    MROW(1, cp##a1, cp)                                                        \
    MROW(2, cp##a2, cp)                                                        \
    MROW(3, cp##a3, cp)                                                        \
    __builtin_amdgcn_s_setprio(0);                                             \
  }

  STAGE_U(0, 0, 0);
  STAGE_U(0, 1, 0);
  asm volatile("s_waitcnt vmcnt(4)" ::: "memory");
  __builtin_amdgcn_s_barrier();
  RD(f, 0, 0);

#pragma unroll 1
  for (int it = 0; it < 36; ++it) {
    int kt1 = it * 2 + 1;
    int kt2 = it < 35 ? it * 2 + 2 : 71;  // clamped; garbage on last iter, unread
    PHASE(0, 1, g, f, STAGE_U(1, 0, kt1));
    PHASE(1, 0, f, g, STAGE_U(1, 1, kt1));
    PHASE(1, 1, g, f, STAGE_U(0, 0, kt2));
    PHASE(0, 0, f, g, STAGE_U(0, 1, kt2));
  }

#undef PHASE
#undef MROW
#undef RD
#undef STAGE_U
#undef STAGE_A
#undef STAGE_B

#pragma unroll
  for (int mi = 0; mi < 4; mi++) {
#pragma unroll
    for (int r = 0; r < 4; r++) {
      int o = o0 + wm * 64 + mi * 16 + lquad * 4 + r;
      float* orow = outb + (size_t)o * 1600;
#pragma unroll
      for (int ni = 0; ni < 7; ni++) {
        int p = p0 + wn * 112 + ni * 16 + lrow;
        if (p < 1600) orow[p] = acc[mi][ni][r];
      }
    }
  }
}

// ---------------------------------------------------------------------------
extern "C" void kernel_launch(void* const* d_in, const int* in_sizes, int n_in,
                              void* d_out, int out_size, void* d_ws, size_t ws_size,
                              hipStream_t stream) {
  const float* ex = (const float*)d_in[0];
  const float* qu = (const float*)d_in[1];
  const float* w_e = (const float*)d_in[2];
  const float* w_q = (const float*)d_in[3];
  const float* w_c1 = (const float*)d_in[4];
  const float* w_c2 = (const float*)d_in[5];
  float* out = (float*)d_out;
  char* ws = (char*)d_ws;

  u16* E     = (u16*)(ws + 0L);            // 81,920,000
  u16* ET    = (u16*)(ws + 81920000L);     // 81,920,000
  u16* xt_e  = (u16*)(ws + 163840000L);    // 26,214,400
  u16* xt_q  = (u16*)(ws + 190054400L);    // 26,214,400
  u16* ecorr = (u16*)(ws + 216268800L);    // 13,107,200
  u16* qcorr = (u16*)(ws + 229376000L);    // 13,107,200
  u16* att_e = (u16*)(ws + 242483200L);    // 28,901,376
  u16* att_q = (u16*)(ws + 271384576L);    // 28,901,376
  float* Zrow = (float*)(ws + 300285952L); // 102,400
  float* Zcol = (float*)(ws + 300388352L); // 102,400
  u16* w_ebf = (u16*)(ws + 300490752L);    // 262,144
  u16* w_qbf = (u16*)(ws + 300752896L);    // 262,144
  u16* wr1   = (u16*)(ws + 301015040L);    // 4,718,592
  u16* wr2   = (u16*)(ws + 305733632L);    // 4,718,592  (total 310,452,224)

  // prep
  transp_cast_x2<<<dim3(50, 16, 32), 256, 0, stream>>>(ex, qu, xt_e, xt_q);
  cast_w<<<dim3(512), 256, 0, stream>>>(w_e, w_q, w_ebf, w_qbf);
  repack_wc<<<dim3(9216, 2), 256, 0, stream>>>(w_c1, w_c2, wr1, wr2);
  // zero pad rings of att_e/att_q (32 x 164 px x 512 ch) + Zrow/Zcol
  zero_pad<<<dim3(33), 256, 0, stream>>>(att_e, Zrow);

  // K1: corr[b][n][o] = sum_c xt[n,c] * w[o,c]
  corr_gemm128<<<dim3(13, 2, 32), 256, 0, stream>>>(
      xt_e, w_ebf, ecorr, xt_q, w_qbf, qcorr);

  // K2: E/ET/Zrow/Zcol fused
  corr_exp128<<<dim3(13, 13, 16), 256, 0, stream>>>(ecorr, qcorr, E, ET, Zrow, Zcol);

  // P5: Z -> 1/Z (Zrow+Zcol contiguous, 51200 floats)
  inv_z<<<dim3(200), 256, 0, stream>>>(Zrow);

  // K4 (fused K3): att_q[p][c] = sum_i E[p,i]*(ex[c,i]/Zcol[i]) ;
  //                att_e[p][c] = sum_i ET[p,i]*(qu[c,i]/Zrow[i])
  att_fuse128<<<dim3(13, 4, 32), 256, 0, stream>>>(
      ex, qu, Zcol, Zrow, E, ET, att_q, att_e);

  // K5: both convs, 256(o)x224(p) single-barrier 4-phase + frag prefetch
  conv_gemmpf<<<dim3(8, 2, 32), 512, 0, stream>>>(wr1, att_e, wr2, att_q, out);
}